// Round 16
// baseline (2586.335 us; speedup 1.0000x reference)
//
#include <hip/hip_runtime.h>
#include <hip/hip_bf16.h>
#include <stdint.h>

// Problem constants
#define Bc   16
#define Tc   12
#define Nc   325
#define Kc   3
#define Hc   64
#define MIc  127
#define LHc  128
#define BNc  (Bc*Nc)        // 5200
#define SUPW 195            // K*(D+H)
#define NCg  (SUPW*2*Hc)    // 24960
#define NCu  (SUPW*Hc)      // 12480
#define MP   163            // ceil(325/2) m-pairs
#define MCH  6              // m-pair chunks of 32
#define GTW  192            // padded Gt width (6*32)

typedef _Float16 half8  __attribute__((ext_vector_type(8)));
typedef _Float16 half2v __attribute__((ext_vector_type(2)));
typedef float    f32x4  __attribute__((ext_vector_type(4)));

static __device__ __forceinline__ float bflo(unsigned int u) {
    return __uint_as_float(u << 16);
}
static __device__ __forceinline__ float bfhi(unsigned int u) {
    return __uint_as_float(u & 0xffff0000u);
}
static __device__ __forceinline__ unsigned short f2bf(float f) {
    unsigned int u = __float_as_uint(f);
    unsigned int r = (u + 0x7fffu + ((u >> 16) & 1u)) >> 16;  // RNE
    return (unsigned short)r;
}
static __device__ __forceinline__ float fdot2f(half2v a, half2v b, float c) {
#if defined(__has_builtin)
#if __has_builtin(__builtin_amdgcn_fdot2)
    return __builtin_amdgcn_fdot2(a, b, c, false);
#else
    return c + (float)a[0] * (float)b[0] + (float)a[1] * (float)b[1];
#endif
#else
    return c + (float)a[0] * (float)b[0] + (float)a[1] * (float)b[1];
#endif
}
static __device__ __forceinline__ unsigned int packh2(float a, float b) {
    half2v h; h[0] = (_Float16)a; h[1] = (_Float16)b;
    return *(unsigned int*)&h;
}

// ---------------------------------------------------------------------------
// Layer-1 of all four meta MLPs, 4 bn rows per block.
__global__ __launch_bounds__(128) void meta1_kernel(
    const float* __restrict__ meta,
    const float* __restrict__ w1a, const float* __restrict__ b1a,
    const float* __restrict__ w1b, const float* __restrict__ b1b,
    const float* __restrict__ w1c, const float* __restrict__ b1c,
    const float* __restrict__ w1d, const float* __restrict__ b1d,
    _Float16* __restrict__ r1a, _Float16* __restrict__ r1b,
    _Float16* __restrict__ r1c, _Float16* __restrict__ r1d)
{
    __shared__ float mrow[4][128];
    const int bn0 = blockIdx.x * 4;
    const int l   = threadIdx.x;
#pragma unroll
    for (int r = 0; r < 4; r++)
        mrow[r][l] = (l < MIc) ? meta[(size_t)(bn0 + r) * MIc + l] : 0.f;
    __syncthreads();

    const float* w1s[4] = {w1a, w1b, w1c, w1d};
    const float* b1s[4] = {b1a, b1b, b1c, b1d};
    _Float16*    os[4]  = {r1a, r1b, r1c, r1d};
#pragma unroll
    for (int s = 0; s < 4; s++) {
        const float* w = w1s[s];
        float acc[4];
        const float bv = b1s[s][l];
#pragma unroll
        for (int r = 0; r < 4; r++) acc[r] = bv;
        for (int m = 0; m < MIc; m++) {
            float wv = w[m * LHc + l];
#pragma unroll
            for (int r = 0; r < 4; r++) acc[r] = fmaf(mrow[r][m], wv, acc[r]);
        }
#pragma unroll
        for (int r = 0; r < 4; r++)
            os[s][(size_t)(bn0 + r) * LHc + l] = (_Float16)fmaxf(acc[r], 0.f);
    }
}

// ---------------------------------------------------------------------------
// w2 [128][NC] f32 -> w2t [NC][128] fp16 (transposed).
__global__ __launch_bounds__(256) void transpose_w2_kernel(
    const float* __restrict__ w2, _Float16* __restrict__ w2t, int NC)
{
    __shared__ float Ls[128][65];
    const int c0 = blockIdx.x * 64;
    const int t  = threadIdx.x;
    {
        const int c  = t & 63;
        const int kb = t >> 6;
        for (int k = kb; k < 128; k += 4) {
            int cc = c0 + c;
            Ls[k][c] = (cc < NC) ? w2[(size_t)k * NC + cc] : 0.f;
        }
    }
    __syncthreads();
    {
        const int k  = t & 127;
        const int ch = t >> 7;
        for (int c = ch; c < 64; c += 2) {
            int cc = c0 + c;
            if (cc < NC) w2t[(size_t)cc * 128 + k] = (_Float16)Ls[k][c];
        }
    }
}

// ---------------------------------------------------------------------------
// MFMA layer-2 GEMM, LDS-staged tiles. Block 256 = 4 waves, 64x64 tile.
template<bool BF16OUT>
__global__ __launch_bounds__(256) void meta2_mfma_kernel(
    const _Float16* __restrict__ A,
    const _Float16* __restrict__ Bt,
    const float* __restrict__ bias,
    void* __restrict__ outp, int NC, int nrows)
{
    __shared__ __align__(16) _Float16 As[64][136];
    __shared__ __align__(16) _Float16 Bs[64][136];
    __shared__ unsigned short Cs[64][72];
    const int t  = threadIdx.x;
    const int w  = t >> 6;
    const int l  = t & 63;
    const int r0 = blockIdx.x * 64;
    const int c0 = blockIdx.y * 64;

#pragma unroll
    for (int p = 0; p < 4; p++) {
        const int gid = p * 256 + t;
        const int row = gid >> 4;
        const int cg  = gid & 15;
        half8 av = (half8)(_Float16)0.f;
        if (r0 + row < nrows) av = *(const half8*)(A + (size_t)(r0 + row) * 128 + cg * 8);
        *(half8*)&As[row][cg * 8] = av;
        half8 bv = *(const half8*)(Bt + (size_t)(c0 + row) * 128 + cg * 8);
        *(half8*)&Bs[row][cg * 8] = bv;
    }
    __syncthreads();

    const int lr = l & 15;
    const int lk = l >> 4;

    half8 aF[4];
#pragma unroll
    for (int kk = 0; kk < 4; kk++)
        aF[kk] = *(const half8*)&As[w * 16 + lr][kk * 32 + lk * 8];

    f32x4 acc[4];
#pragma unroll
    for (int j = 0; j < 4; j++) acc[j] = (f32x4)0.f;

#pragma unroll
    for (int j = 0; j < 4; j++)
#pragma unroll
        for (int kk = 0; kk < 4; kk++) {
            half8 bF = *(const half8*)&Bs[j * 16 + lr][kk * 32 + lk * 8];
            acc[j] = __builtin_amdgcn_mfma_f32_16x16x32_f16(aF[kk], bF, acc[j], 0, 0, 0);
        }

    if (BF16OUT) {
#pragma unroll
        for (int j = 0; j < 4; j++) {
            const float bv = bias[c0 + j * 16 + lr];
#pragma unroll
            for (int q = 0; q < 4; q++)
                Cs[w * 16 + lk * 4 + q][j * 16 + lr] = f2bf(acc[j][q] + bv);
        }
        __syncthreads();
        const int rl  = t >> 2;
        const int cp  = t & 3;
        const int row = r0 + rl;
        if (row < nrows) {
            const uint4* src = (const uint4*)&Cs[rl][cp * 16];
            uint4* dst = (uint4*)((unsigned short*)outp + (size_t)row * NC + c0 + cp * 16);
            dst[0] = src[0];
            dst[1] = src[1];
        }
    } else {
#pragma unroll
        for (int j = 0; j < 4; j++) {
            const int col = c0 + j * 16 + lr;
            const float bv = bias[col];
#pragma unroll
            for (int q = 0; q < 4; q++) {
                const int row = r0 + w * 16 + lk * 4 + q;
                if (row < nrows)
                    ((float*)outp)[(size_t)row * NC + col] = acc[j][q] + bv;
            }
        }
    }
}

// ---------------------------------------------------------------------------
// gx tiled: GX[tt,b,k,n] = sum_m G[k,n,m] * x[tb,m], tb = b*Tc+tt.
__global__ __launch_bounds__(256) void gx_kernel(
    const float* __restrict__ G, const float* __restrict__ x,
    float* __restrict__ GX)
{
    __shared__ __align__(16) float Gs[32][36];
    __shared__ __align__(16) float Xs[32][65];
    const int k   = blockIdx.x;
    const int n0  = blockIdx.y * 32;
    const int tb0 = blockIdx.z * 64;
    const int t   = threadIdx.x;
    const int j   = t & 63;
    const int ng  = t >> 6;

    float acc[8] = {0.f,0.f,0.f,0.f,0.f,0.f,0.f,0.f};

    for (int mc = 0; mc < 11; mc++) {
        const int m0 = mc * 32;
        __syncthreads();
        {
            const int ln  = t >> 3;
            const int lm0 = (t & 7) * 4;
            const int gn  = n0 + ln;
#pragma unroll
            for (int u = 0; u < 4; u++) {
                int m = m0 + lm0 + u;
                Gs[lm0 + u][ln] = (gn < Nc && m < Nc) ? G[((size_t)k * Nc + gn) * Nc + m] : 0.f;
            }
        }
        {
            const int row = t >> 2;
            const int ms  = (t & 3) * 8;
            const float* xr = x + (size_t)(tb0 + row) * Nc;
#pragma unroll
            for (int u = 0; u < 8; u++) {
                int m = m0 + ms + u;
                Xs[ms + u][row] = (m < Nc) ? xr[m] : 0.f;
            }
        }
        __syncthreads();
#pragma unroll
        for (int mm = 0; mm < 32; mm++) {
            float xv = Xs[mm][j];
            float4 ga = *(const float4*)&Gs[mm][ng * 8];
            float4 gb = *(const float4*)&Gs[mm][ng * 8 + 4];
            acc[0] = fmaf(ga.x, xv, acc[0]);
            acc[1] = fmaf(ga.y, xv, acc[1]);
            acc[2] = fmaf(ga.z, xv, acc[2]);
            acc[3] = fmaf(ga.w, xv, acc[3]);
            acc[4] = fmaf(gb.x, xv, acc[4]);
            acc[5] = fmaf(gb.y, xv, acc[5]);
            acc[6] = fmaf(gb.z, xv, acc[6]);
            acc[7] = fmaf(gb.w, xv, acc[7]);
        }
    }

    const int tb = tb0 + j;
    const int b  = tb / Tc;
    const int tv = tb % Tc;
    float* gxp = GX + (((size_t)tv * Bc + b) * Kc + k) * Nc;
#pragma unroll
    for (int i = 0; i < 8; i++) {
        int n = n0 + ng * 8 + i;
        if (n < Nc) gxp[n] = acc[i];
    }
}

// ---------------------------------------------------------------------------
// Shared device bodies (G rows pre-staged once in Gt[3][GTW]).
static __device__ __forceinline__ void stage_g_rows(
    const float* __restrict__ G, int n, unsigned int (&Gt)[3][GTW])
{
    const int t = threadIdx.x;
    for (int idx = t; idx < 3 * GTW; idx += 256) {
        const int kk = idx / GTW;
        const int mp = idx % GTW;
        const float* gr = G + ((size_t)kk * Nc + n) * Nc;
        const int m0 = 2 * mp;
        float g0 = (m0 < Nc)     ? gr[m0]     : 0.f;
        float g1 = (m0 + 1 < Nc) ? gr[m0 + 1] : 0.f;
        Gt[kk][mp] = packh2(g0, g1);
    }
}

static __device__ __forceinline__ void gates_body(
    const float* __restrict__ hbuf, const float* __restrict__ GX,
    const unsigned short* __restrict__ Wg, const float* __restrict__ bg,
    float* __restrict__ zbuf, float* __restrict__ rhbuf,
    int tt, int bStart, int bl, int n,
    unsigned int (&Hc2)[32][64], const unsigned int (&Gt)[3][GTW],
    float (&supL)[208], float (&pS)[4][16][8])
{
    const int t = threadIdx.x;
    const int lane = t & 63;
    const int w = t >> 6;
    const int j = lane;
    const int b = bStart + bl;
    const float* hb = hbuf + (size_t)b * Nc * Hc;
    float accA = 0.f;

    for (int c6 = 0; c6 < MCH; c6++) {
        const int mpB = c6 * 32;
        __syncthreads();
#pragma unroll
        for (int p = 0; p < 8; p++) {
            const int idx = p * 256 + t;
            const int mpl = idx >> 6;
            const int jj  = idx & 63;
            const int m0  = 2 * (mpB + mpl);
            float h0 = (m0 < Nc)     ? hb[(size_t)m0 * Hc + jj]       : 0.f;
            float h1 = (m0 + 1 < Nc) ? hb[(size_t)(m0 + 1) * Hc + jj] : 0.f;
            Hc2[mpl][jj] = packh2(h0, h1);
        }
        __syncthreads();
        if (w < 3) {
            const unsigned int* gp = &Gt[w][mpB];
#pragma unroll
            for (int mpl = 0; mpl < 32; mpl++) {
                unsigned int hu = Hc2[mpl][j];
                unsigned int gu = gp[mpl];
                accA = fdot2f(*(half2v*)&gu, *(half2v*)&hu, accA);
            }
        }
    }
    if (w < 3) supL[w * 65 + 1 + j] = accA;
    if (t < 3)
        supL[t * 65] = GX[(((size_t)tt * Bc + b) * Kc + t) * Nc + n];
    __syncthreads();

    const int c = lane & 15;
    const int g = lane >> 4;
    const unsigned short* wrow = Wg + ((size_t)bl * Nc + n) * NCg;
    float a2[8] = {0.f,0.f,0.f,0.f,0.f,0.f,0.f,0.f};

#pragma unroll
    for (int i0 = 0; i0 < SUPW; i0 += 16) {
        const int i = i0 + w * 4 + g;
        if (i < SUPW) {
            uint4 v = *(const uint4*)(wrow + (size_t)i * 128 + c * 8);
            float s = supL[i];
            a2[0] = fmaf(s, bflo(v.x), a2[0]);
            a2[1] = fmaf(s, bfhi(v.x), a2[1]);
            a2[2] = fmaf(s, bflo(v.y), a2[2]);
            a2[3] = fmaf(s, bfhi(v.y), a2[3]);
            a2[4] = fmaf(s, bflo(v.z), a2[4]);
            a2[5] = fmaf(s, bfhi(v.z), a2[5]);
            a2[6] = fmaf(s, bflo(v.w), a2[6]);
            a2[7] = fmaf(s, bfhi(v.w), a2[7]);
        }
    }
#pragma unroll
    for (int e = 0; e < 8; e++) {
        a2[e] += __shfl_xor(a2[e], 16, 64);
        a2[e] += __shfl_xor(a2[e], 32, 64);
    }
    if (g == 0) {
#pragma unroll
        for (int e = 0; e < 8; e++) pS[w][c][e] = a2[e];
    }
    __syncthreads();
    if (w == 0 && g == 0) {
        const size_t bng = (size_t)b * Nc + n;
#pragma unroll
        for (int e = 0; e < 8; e++) {
            const int h2 = c * 8 + e;
            const float pre = pS[0][c][e] + pS[1][c][e] + pS[2][c][e] + pS[3][c][e]
                            + bg[bng * (2 * Hc) + h2];
            const float zr  = 1.f / (1.f + expf(-pre));
            if (h2 < Hc) zbuf[bng * Hc + h2] = zr;
            else {
                const int hh = h2 - Hc;
                rhbuf[bng * Hc + hh] = zr * hbuf[bng * Hc + hh];
            }
        }
    }
}

static __device__ __forceinline__ void update_body(
    float* __restrict__ hbuf, const float* __restrict__ rhbuf,
    const float* __restrict__ GX,
    const unsigned short* __restrict__ Wu, const float* __restrict__ bu,
    const float* __restrict__ zbuf, float* __restrict__ outp,
    int tt, int bStart, int bl, int n,
    unsigned int (&Hc2)[32][64], const unsigned int (&Gt)[3][GTW],
    float (&supL)[208], float (&pS)[4][16][8])
{
    const int t = threadIdx.x;
    const int lane = t & 63;
    const int w = t >> 6;
    const int j = lane;
    const int b = bStart + bl;
    const float* hb = rhbuf + (size_t)b * Nc * Hc;
    float accA = 0.f;

    for (int c6 = 0; c6 < MCH; c6++) {
        const int mpB = c6 * 32;
        __syncthreads();
#pragma unroll
        for (int p = 0; p < 8; p++) {
            const int idx = p * 256 + t;
            const int mpl = idx >> 6;
            const int jj  = idx & 63;
            const int m0  = 2 * (mpB + mpl);
            float h0 = (m0 < Nc)     ? hb[(size_t)m0 * Hc + jj]       : 0.f;
            float h1 = (m0 + 1 < Nc) ? hb[(size_t)(m0 + 1) * Hc + jj] : 0.f;
            Hc2[mpl][jj] = packh2(h0, h1);
        }
        __syncthreads();
        if (w < 3) {
            const unsigned int* gp = &Gt[w][mpB];
#pragma unroll
            for (int mpl = 0; mpl < 32; mpl++) {
                unsigned int hu = Hc2[mpl][j];
                unsigned int gu = gp[mpl];
                accA = fdot2f(*(half2v*)&gu, *(half2v*)&hu, accA);
            }
        }
    }
    if (w < 3) supL[w * 65 + 1 + j] = accA;
    if (t < 3)
        supL[t * 65] = GX[(((size_t)tt * Bc + b) * Kc + t) * Nc + n];
    __syncthreads();

    const int c = lane & 7;
    const int g = lane >> 3;
    const unsigned short* wrow = Wu + ((size_t)bl * Nc + n) * NCu;
    float a2[8] = {0.f,0.f,0.f,0.f,0.f,0.f,0.f,0.f};

#pragma unroll
    for (int i0 = 0; i0 < SUPW; i0 += 32) {
        const int i = i0 + w * 8 + g;
        if (i < SUPW) {
            uint4 v = *(const uint4*)(wrow + (size_t)i * 64 + c * 8);
            float s = supL[i];
            a2[0] = fmaf(s, bflo(v.x), a2[0]);
            a2[1] = fmaf(s, bfhi(v.x), a2[1]);
            a2[2] = fmaf(s, bflo(v.y), a2[2]);
            a2[3] = fmaf(s, bfhi(v.y), a2[3]);
            a2[4] = fmaf(s, bflo(v.z), a2[4]);
            a2[5] = fmaf(s, bfhi(v.z), a2[5]);
            a2[6] = fmaf(s, bflo(v.w), a2[6]);
            a2[7] = fmaf(s, bfhi(v.w), a2[7]);
        }
    }
#pragma unroll
    for (int e = 0; e < 8; e++) {
        a2[e] += __shfl_xor(a2[e], 8, 64);
        a2[e] += __shfl_xor(a2[e], 16, 64);
        a2[e] += __shfl_xor(a2[e], 32, 64);
    }
    if (g == 0) {
#pragma unroll
        for (int e = 0; e < 8; e++) pS[w][c][e] = a2[e];
    }
    __syncthreads();
    if (w == 0 && g == 0) {
        const size_t bng = (size_t)b * Nc + n;
#pragma unroll
        for (int e = 0; e < 8; e++) {
            const int hh = c * 8 + e;
            const float npre = pS[0][c][e] + pS[1][c][e] + pS[2][c][e] + pS[3][c][e]
                             + bu[bng * Hc + hh];
            const float nn_t = tanhf(npre);
            const float z    = zbuf[bng * Hc + hh];
            const float hold = hbuf[bng * Hc + hh];
            const float hnew = fmaf(z, nn_t - hold, hold);
            hbuf[bng * Hc + hh] = hnew;
            outp[(((size_t)b * Tc + tt) * Nc + n) * Hc + hh] = hnew;
            if (tt == Tc - 1)
                outp[(size_t)Bc * Tc * Nc * Hc + bng * Hc + hh] = hnew;
        }
    }
}

// ---------------------------------------------------------------------------
// Standalone fused kernels (one node per block; G staged once per kernel).
__global__ __launch_bounds__(256, 6) void fused_gates_kernel(
    const float* __restrict__ G, const float* __restrict__ hbuf,
    const float* __restrict__ GX, const unsigned short* __restrict__ Wg,
    const float* __restrict__ bg, float* __restrict__ zbuf,
    float* __restrict__ rhbuf, int tt, int bStart)
{
    __shared__ unsigned int Hc2[32][64];
    __shared__ unsigned int Gt1[3][GTW];
    __shared__ float supL[208];
    __shared__ float pS[4][16][8];
    const int bx = blockIdx.x;
    const int bl = bx / Nc;
    const int n  = bx % Nc;
    stage_g_rows(G, n, Gt1);
    gates_body(hbuf, GX, Wg, bg, zbuf, rhbuf, tt, bStart, bl, n,
               Hc2, Gt1, supL, pS);
}

__global__ __launch_bounds__(256, 6) void fused_update_kernel(
    const float* __restrict__ G, const float* __restrict__ rhbuf,
    const float* __restrict__ GX, const unsigned short* __restrict__ Wu,
    const float* __restrict__ bu, const float* __restrict__ zbuf,
    float* __restrict__ hbuf, float* __restrict__ outp, int tt, int bStart)
{
    __shared__ unsigned int Hc2[32][64];
    __shared__ unsigned int Gt1[3][GTW];
    __shared__ float supL[208];
    __shared__ float pS[4][16][8];
    const int bx = blockIdx.x;
    const int bl = bx / Nc;
    const int n  = bx % Nc;
    stage_g_rows(G, n, Gt1);
    update_body(hbuf, rhbuf, GX, Wu, bu, zbuf, outp, tt, bStart, bl, n,
                Hc2, Gt1, supL, pS);
}

// ---------------------------------------------------------------------------
extern "C" void kernel_launch(void* const* d_in, const int* in_sizes, int n_in,
                              void* d_out, int out_size, void* d_ws, size_t ws_size,
                              hipStream_t stream)
{
    const float* G        = (const float*)d_in[0];
    const float* x        = (const float*)d_in[1];
    const float* meta     = (const float*)d_in[2];
    const float* lwg_w1   = (const float*)d_in[3];
    const float* lwg_b1   = (const float*)d_in[4];
    const float* lwg_w2   = (const float*)d_in[5];
    const float* lwg_b2   = (const float*)d_in[6];
    const float* lbg_w1   = (const float*)d_in[7];
    const float* lbg_b1   = (const float*)d_in[8];
    const float* lbg_w2   = (const float*)d_in[9];
    const float* lbg_b2   = (const float*)d_in[10];
    const float* lwu_w1   = (const float*)d_in[11];
    const float* lwu_b1   = (const float*)d_in[12];
    const float* lwu_w2   = (const float*)d_in[13];
    const float* lwu_b2   = (const float*)d_in[14];
    const float* lbu_w1   = (const float*)d_in[15];
    const float* lbu_b1   = (const float*)d_in[16];
    const float* lbu_w2   = (const float*)d_in[17];
    const float* lbu_b2   = (const float*)d_in[18];

    auto alignup = [](size_t b) { return (b + 255) & ~(size_t)255; };
    const size_t miscBytes =
        alignup((size_t)BNc * 2 * Hc * 4) +
        alignup((size_t)BNc * Hc * 4) +
        4 * alignup((size_t)BNc * LHc * 2) +
        alignup((size_t)NCg * 128 * 2) +
        alignup((size_t)NCu * 128 * 2) +
        alignup((size_t)128 * 128 * 2) +
        alignup((size_t)64 * 128 * 2) +
        alignup((size_t)Tc * Bc * Kc * Nc * 4) +
        3 * alignup((size_t)BNc * Hc * 4);

    // Bch = 4: per-chunk weight set (Wg 65 MB + Wu 32.5 MB) is L3-resident
    // across the 12 timestep reuses (256 MB Infinity Cache).
    int Bch = 0;
    const int cand[3] = {4, 2, 1};
    for (int ci = 0; ci < 3; ci++) {
        size_t BNch = (size_t)cand[ci] * Nc;
        size_t need = miscBytes + alignup(BNch * NCg * 2) + alignup(BNch * NCu * 2);
        if (need <= ws_size) { Bch = cand[ci]; break; }
    }
    if (Bch == 0) return;
    const int nChunks = Bc / Bch;
    const int BNch    = Bch * Nc;

    char* ws = (char*)d_ws;
    size_t off = 0;
    auto alloc = [&](size_t bytes) -> char* {
        char* p = ws + off;
        off += (bytes + 255) & ~(size_t)255;
        return p;
    };
    unsigned short* Wg = (unsigned short*)alloc((size_t)BNch * NCg * 2);
    unsigned short* Wu = (unsigned short*)alloc((size_t)BNch * NCu * 2);
    float* bgbuf  = (float*)alloc((size_t)BNc * 2 * Hc * 4);
    float* bubuf  = (float*)alloc((size_t)BNc * Hc * 4);
    _Float16* r1g  = (_Float16*)alloc((size_t)BNc * LHc * 2);
    _Float16* r1bg = (_Float16*)alloc((size_t)BNc * LHc * 2);
    _Float16* r1u  = (_Float16*)alloc((size_t)BNc * LHc * 2);
    _Float16* r1bu = (_Float16*)alloc((size_t)BNc * LHc * 2);
    _Float16* w2tg  = (_Float16*)alloc((size_t)NCg * 128 * 2);
    _Float16* w2tu  = (_Float16*)alloc((size_t)NCu * 128 * 2);
    _Float16* w2tbg = (_Float16*)alloc((size_t)128 * 128 * 2);
    _Float16* w2tbu = (_Float16*)alloc((size_t)64 * 128 * 2);
    float* GX    = (float*)alloc((size_t)Tc * Bc * Kc * Nc * 4);
    float* hbuf  = (float*)alloc((size_t)BNc * Hc * 4);
    float* zbuf  = (float*)alloc((size_t)BNc * Hc * 4);
    float* rhbuf = (float*)alloc((size_t)BNc * Hc * 4);
    if (off > ws_size) return;

    float* out = (float*)d_out;

    hipMemsetAsync(hbuf, 0, (size_t)BNc * Hc * 4, stream);

    meta1_kernel<<<BNc / 4, 128, 0, stream>>>(
        meta, lwg_w1, lwg_b1, lbg_w1, lbg_b1, lwu_w1, lwu_b1, lbu_w1, lbu_b1,
        r1g, r1bg, r1u, r1bu);

    transpose_w2_kernel<<<(NCg + 63) / 64, 256, 0, stream>>>(lwg_w2, w2tg, NCg);
    transpose_w2_kernel<<<(NCu + 63) / 64, 256, 0, stream>>>(lwu_w2, w2tu, NCu);
    transpose_w2_kernel<<<2, 256, 0, stream>>>(lbg_w2, w2tbg, 2 * Hc);
    transpose_w2_kernel<<<1, 256, 0, stream>>>(lbu_w2, w2tbu, Hc);

    meta2_mfma_kernel<false><<<dim3((BNc + 63) / 64, (2 * Hc) / 64), 256, 0, stream>>>(
        r1bg, w2tbg, lbg_b2, (void*)bgbuf, 2 * Hc, BNc);
    meta2_mfma_kernel<false><<<dim3((BNc + 63) / 64, Hc / 64), 256, 0, stream>>>(
        r1bu, w2tbu, lbu_b2, (void*)bubuf, Hc, BNc);

    gx_kernel<<<dim3(Kc, 11, 3), 256, 0, stream>>>(G, x, GX);

    for (int ch = 0; ch < nChunks; ch++) {
        const int bStart  = ch * Bch;
        const int bnStart = bStart * Nc;

        meta2_mfma_kernel<true><<<dim3((BNch + 63) / 64, NCg / 64), 256, 0, stream>>>(
            r1g + (size_t)bnStart * LHc, w2tg, lwg_b2, (void*)Wg, NCg, BNch);
        meta2_mfma_kernel<true><<<dim3((BNch + 63) / 64, NCu / 64), 256, 0, stream>>>(
            r1u + (size_t)bnStart * LHc, w2tu, lwu_b2, (void*)Wu, NCu, BNch);

        for (int tt = 0; tt < Tc; tt++) {
            fused_gates_kernel<<<BNch, 256, 0, stream>>>(
                G, hbuf, GX, Wg, bgbuf, zbuf, rhbuf, tt, bStart);
            fused_update_kernel<<<BNch, 256, 0, stream>>>(
                G, rhbuf, GX, Wu, bubuf, zbuf, hbuf, out, tt, bStart);
        }
    }
}

// Round 17
// 2135.654 us; speedup vs baseline: 1.2110x; 1.2110x over previous
//
#include <hip/hip_runtime.h>
#include <hip/hip_bf16.h>
#include <stdint.h>

// Problem constants
#define Bc   16
#define Tc   12
#define Nc   325
#define Kc   3
#define Hc   64
#define MIc  127
#define LHc  128
#define BNc  (Bc*Nc)        // 5200
#define SUPW 195            // K*(D+H)
#define NCg  (SUPW*2*Hc)    // 24960
#define NCu  (SUPW*Hc)      // 12480
#define MP   163            // ceil(325/2) m-pairs
#define MCH  6              // m-pair chunks of 32
#define GTW  192            // padded Gt width (6*32)

typedef _Float16 half8  __attribute__((ext_vector_type(8)));
typedef _Float16 half2v __attribute__((ext_vector_type(2)));
typedef float    f32x4  __attribute__((ext_vector_type(4)));

static __device__ __forceinline__ float bflo(unsigned int u) {
    return __uint_as_float(u << 16);
}
static __device__ __forceinline__ float bfhi(unsigned int u) {
    return __uint_as_float(u & 0xffff0000u);
}
static __device__ __forceinline__ unsigned short f2bf(float f) {
    unsigned int u = __float_as_uint(f);
    unsigned int r = (u + 0x7fffu + ((u >> 16) & 1u)) >> 16;  // RNE
    return (unsigned short)r;
}
static __device__ __forceinline__ float fdot2f(half2v a, half2v b, float c) {
#if defined(__has_builtin)
#if __has_builtin(__builtin_amdgcn_fdot2)
    return __builtin_amdgcn_fdot2(a, b, c, false);
#else
    return c + (float)a[0] * (float)b[0] + (float)a[1] * (float)b[1];
#endif
#else
    return c + (float)a[0] * (float)b[0] + (float)a[1] * (float)b[1];
#endif
}
static __device__ __forceinline__ unsigned int packh2(float a, float b) {
    half2v h; h[0] = (_Float16)a; h[1] = (_Float16)b;
    return *(unsigned int*)&h;
}

// ---------------------------------------------------------------------------
// Layer-1 of all four meta MLPs, 4 bn rows per block.
__global__ __launch_bounds__(128) void meta1_kernel(
    const float* __restrict__ meta,
    const float* __restrict__ w1a, const float* __restrict__ b1a,
    const float* __restrict__ w1b, const float* __restrict__ b1b,
    const float* __restrict__ w1c, const float* __restrict__ b1c,
    const float* __restrict__ w1d, const float* __restrict__ b1d,
    _Float16* __restrict__ r1a, _Float16* __restrict__ r1b,
    _Float16* __restrict__ r1c, _Float16* __restrict__ r1d)
{
    __shared__ float mrow[4][128];
    const int bn0 = blockIdx.x * 4;
    const int l   = threadIdx.x;
#pragma unroll
    for (int r = 0; r < 4; r++)
        mrow[r][l] = (l < MIc) ? meta[(size_t)(bn0 + r) * MIc + l] : 0.f;
    __syncthreads();

    const float* w1s[4] = {w1a, w1b, w1c, w1d};
    const float* b1s[4] = {b1a, b1b, b1c, b1d};
    _Float16*    os[4]  = {r1a, r1b, r1c, r1d};
#pragma unroll
    for (int s = 0; s < 4; s++) {
        const float* w = w1s[s];
        float acc[4];
        const float bv = b1s[s][l];
#pragma unroll
        for (int r = 0; r < 4; r++) acc[r] = bv;
        for (int m = 0; m < MIc; m++) {
            float wv = w[m * LHc + l];
#pragma unroll
            for (int r = 0; r < 4; r++) acc[r] = fmaf(mrow[r][m], wv, acc[r]);
        }
#pragma unroll
        for (int r = 0; r < 4; r++)
            os[s][(size_t)(bn0 + r) * LHc + l] = (_Float16)fmaxf(acc[r], 0.f);
    }
}

// ---------------------------------------------------------------------------
// w2 [128][NC] f32 -> w2t [NC][128] fp16 (transposed).
__global__ __launch_bounds__(256) void transpose_w2_kernel(
    const float* __restrict__ w2, _Float16* __restrict__ w2t, int NC)
{
    __shared__ float Ls[128][65];
    const int c0 = blockIdx.x * 64;
    const int t  = threadIdx.x;
    {
        const int c  = t & 63;
        const int kb = t >> 6;
        for (int k = kb; k < 128; k += 4) {
            int cc = c0 + c;
            Ls[k][c] = (cc < NC) ? w2[(size_t)k * NC + cc] : 0.f;
        }
    }
    __syncthreads();
    {
        const int k  = t & 127;
        const int ch = t >> 7;
        for (int c = ch; c < 64; c += 2) {
            int cc = c0 + c;
            if (cc < NC) w2t[(size_t)cc * 128 + k] = (_Float16)Ls[k][c];
        }
    }
}

// ---------------------------------------------------------------------------
// MFMA layer-2 GEMM, LDS-staged tiles. Block 256 = 4 waves, 64x64 tile.
template<bool BF16OUT>
__global__ __launch_bounds__(256) void meta2_mfma_kernel(
    const _Float16* __restrict__ A,
    const _Float16* __restrict__ Bt,
    const float* __restrict__ bias,
    void* __restrict__ outp, int NC, int nrows)
{
    __shared__ __align__(16) _Float16 As[64][136];
    __shared__ __align__(16) _Float16 Bs[64][136];
    __shared__ unsigned short Cs[64][72];
    const int t  = threadIdx.x;
    const int w  = t >> 6;
    const int l  = t & 63;
    const int r0 = blockIdx.x * 64;
    const int c0 = blockIdx.y * 64;

#pragma unroll
    for (int p = 0; p < 4; p++) {
        const int gid = p * 256 + t;
        const int row = gid >> 4;
        const int cg  = gid & 15;
        half8 av = (half8)(_Float16)0.f;
        if (r0 + row < nrows) av = *(const half8*)(A + (size_t)(r0 + row) * 128 + cg * 8);
        *(half8*)&As[row][cg * 8] = av;
        half8 bv = *(const half8*)(Bt + (size_t)(c0 + row) * 128 + cg * 8);
        *(half8*)&Bs[row][cg * 8] = bv;
    }
    __syncthreads();

    const int lr = l & 15;
    const int lk = l >> 4;

    half8 aF[4];
#pragma unroll
    for (int kk = 0; kk < 4; kk++)
        aF[kk] = *(const half8*)&As[w * 16 + lr][kk * 32 + lk * 8];

    f32x4 acc[4];
#pragma unroll
    for (int j = 0; j < 4; j++) acc[j] = (f32x4)0.f;

#pragma unroll
    for (int j = 0; j < 4; j++)
#pragma unroll
        for (int kk = 0; kk < 4; kk++) {
            half8 bF = *(const half8*)&Bs[j * 16 + lr][kk * 32 + lk * 8];
            acc[j] = __builtin_amdgcn_mfma_f32_16x16x32_f16(aF[kk], bF, acc[j], 0, 0, 0);
        }

    if (BF16OUT) {
#pragma unroll
        for (int j = 0; j < 4; j++) {
            const float bv = bias[c0 + j * 16 + lr];
#pragma unroll
            for (int q = 0; q < 4; q++)
                Cs[w * 16 + lk * 4 + q][j * 16 + lr] = f2bf(acc[j][q] + bv);
        }
        __syncthreads();
        const int rl  = t >> 2;
        const int cp  = t & 3;
        const int row = r0 + rl;
        if (row < nrows) {
            const uint4* src = (const uint4*)&Cs[rl][cp * 16];
            uint4* dst = (uint4*)((unsigned short*)outp + (size_t)row * NC + c0 + cp * 16);
            dst[0] = src[0];
            dst[1] = src[1];
        }
    } else {
#pragma unroll
        for (int j = 0; j < 4; j++) {
            const int col = c0 + j * 16 + lr;
            const float bv = bias[col];
#pragma unroll
            for (int q = 0; q < 4; q++) {
                const int row = r0 + w * 16 + lk * 4 + q;
                if (row < nrows)
                    ((float*)outp)[(size_t)row * NC + col] = acc[j][q] + bv;
            }
        }
    }
}

// ---------------------------------------------------------------------------
// gx tiled: GX[tt,b,k,n] = sum_m G[k,n,m] * x[tb,m], tb = b*Tc+tt.
__global__ __launch_bounds__(256) void gx_kernel(
    const float* __restrict__ G, const float* __restrict__ x,
    float* __restrict__ GX)
{
    __shared__ __align__(16) float Gs[32][36];
    __shared__ __align__(16) float Xs[32][65];
    const int k   = blockIdx.x;
    const int n0  = blockIdx.y * 32;
    const int tb0 = blockIdx.z * 64;
    const int t   = threadIdx.x;
    const int j   = t & 63;
    const int ng  = t >> 6;

    float acc[8] = {0.f,0.f,0.f,0.f,0.f,0.f,0.f,0.f};

    for (int mc = 0; mc < 11; mc++) {
        const int m0 = mc * 32;
        __syncthreads();
        {
            const int ln  = t >> 3;
            const int lm0 = (t & 7) * 4;
            const int gn  = n0 + ln;
#pragma unroll
            for (int u = 0; u < 4; u++) {
                int m = m0 + lm0 + u;
                Gs[lm0 + u][ln] = (gn < Nc && m < Nc) ? G[((size_t)k * Nc + gn) * Nc + m] : 0.f;
            }
        }
        {
            const int row = t >> 2;
            const int ms  = (t & 3) * 8;
            const float* xr = x + (size_t)(tb0 + row) * Nc;
#pragma unroll
            for (int u = 0; u < 8; u++) {
                int m = m0 + ms + u;
                Xs[ms + u][row] = (m < Nc) ? xr[m] : 0.f;
            }
        }
        __syncthreads();
#pragma unroll
        for (int mm = 0; mm < 32; mm++) {
            float xv = Xs[mm][j];
            float4 ga = *(const float4*)&Gs[mm][ng * 8];
            float4 gb = *(const float4*)&Gs[mm][ng * 8 + 4];
            acc[0] = fmaf(ga.x, xv, acc[0]);
            acc[1] = fmaf(ga.y, xv, acc[1]);
            acc[2] = fmaf(ga.z, xv, acc[2]);
            acc[3] = fmaf(ga.w, xv, acc[3]);
            acc[4] = fmaf(gb.x, xv, acc[4]);
            acc[5] = fmaf(gb.y, xv, acc[5]);
            acc[6] = fmaf(gb.z, xv, acc[6]);
            acc[7] = fmaf(gb.w, xv, acc[7]);
        }
    }

    const int tb = tb0 + j;
    const int b  = tb / Tc;
    const int tv = tb % Tc;
    float* gxp = GX + (((size_t)tv * Bc + b) * Kc + k) * Nc;
#pragma unroll
    for (int i = 0; i < 8; i++) {
        int n = n0 + ng * 8 + i;
        if (n < Nc) gxp[n] = acc[i];
    }
}

// ---------------------------------------------------------------------------
// Shared device bodies (G rows pre-staged once in Gt[3][GTW]).
static __device__ __forceinline__ void stage_g_rows(
    const float* __restrict__ G, int n, unsigned int (&Gt)[3][GTW])
{
    const int t = threadIdx.x;
    for (int idx = t; idx < 3 * GTW; idx += 256) {
        const int kk = idx / GTW;
        const int mp = idx % GTW;
        const float* gr = G + ((size_t)kk * Nc + n) * Nc;
        const int m0 = 2 * mp;
        float g0 = (m0 < Nc)     ? gr[m0]     : 0.f;
        float g1 = (m0 + 1 < Nc) ? gr[m0 + 1] : 0.f;
        Gt[kk][mp] = packh2(g0, g1);
    }
}

static __device__ __forceinline__ void gates_body(
    const float* __restrict__ hbuf, const float* __restrict__ GX,
    const unsigned short* __restrict__ Wg, const float* __restrict__ bg,
    float* __restrict__ zbuf, float* __restrict__ rhbuf,
    int tt, int bStart, int bl, int n,
    unsigned int (&Hc2)[32][64], const unsigned int (&Gt)[3][GTW],
    float (&supL)[208], float (&pS)[4][16][8])
{
    const int t = threadIdx.x;
    const int lane = t & 63;
    const int w = t >> 6;
    const int j = lane;
    const int b = bStart + bl;
    const float* hb = hbuf + (size_t)b * Nc * Hc;
    float accA = 0.f;

    for (int c6 = 0; c6 < MCH; c6++) {
        const int mpB = c6 * 32;
        __syncthreads();
#pragma unroll
        for (int p = 0; p < 8; p++) {
            const int idx = p * 256 + t;
            const int mpl = idx >> 6;
            const int jj  = idx & 63;
            const int m0  = 2 * (mpB + mpl);
            float h0 = (m0 < Nc)     ? hb[(size_t)m0 * Hc + jj]       : 0.f;
            float h1 = (m0 + 1 < Nc) ? hb[(size_t)(m0 + 1) * Hc + jj] : 0.f;
            Hc2[mpl][jj] = packh2(h0, h1);
        }
        __syncthreads();
        if (w < 3) {
            const unsigned int* gp = &Gt[w][mpB];
#pragma unroll
            for (int mpl = 0; mpl < 32; mpl++) {
                unsigned int hu = Hc2[mpl][j];
                unsigned int gu = gp[mpl];
                accA = fdot2f(*(half2v*)&gu, *(half2v*)&hu, accA);
            }
        }
    }
    if (w < 3) supL[w * 65 + 1 + j] = accA;
    if (t < 3)
        supL[t * 65] = GX[(((size_t)tt * Bc + b) * Kc + t) * Nc + n];
    __syncthreads();

    const int c = lane & 15;
    const int g = lane >> 4;
    const unsigned short* wrow = Wg + ((size_t)bl * Nc + n) * NCg;
    float a2[8] = {0.f,0.f,0.f,0.f,0.f,0.f,0.f,0.f};

#pragma unroll
    for (int i0 = 0; i0 < SUPW; i0 += 16) {
        const int i = i0 + w * 4 + g;
        if (i < SUPW) {
            uint4 v = *(const uint4*)(wrow + (size_t)i * 128 + c * 8);
            float s = supL[i];
            a2[0] = fmaf(s, bflo(v.x), a2[0]);
            a2[1] = fmaf(s, bfhi(v.x), a2[1]);
            a2[2] = fmaf(s, bflo(v.y), a2[2]);
            a2[3] = fmaf(s, bfhi(v.y), a2[3]);
            a2[4] = fmaf(s, bflo(v.z), a2[4]);
            a2[5] = fmaf(s, bfhi(v.z), a2[5]);
            a2[6] = fmaf(s, bflo(v.w), a2[6]);
            a2[7] = fmaf(s, bfhi(v.w), a2[7]);
        }
    }
#pragma unroll
    for (int e = 0; e < 8; e++) {
        a2[e] += __shfl_xor(a2[e], 16, 64);
        a2[e] += __shfl_xor(a2[e], 32, 64);
    }
    if (g == 0) {
#pragma unroll
        for (int e = 0; e < 8; e++) pS[w][c][e] = a2[e];
    }
    __syncthreads();
    if (w == 0 && g == 0) {
        const size_t bng = (size_t)b * Nc + n;
#pragma unroll
        for (int e = 0; e < 8; e++) {
            const int h2 = c * 8 + e;
            const float pre = pS[0][c][e] + pS[1][c][e] + pS[2][c][e] + pS[3][c][e]
                            + bg[bng * (2 * Hc) + h2];
            const float zr  = 1.f / (1.f + expf(-pre));
            if (h2 < Hc) zbuf[bng * Hc + h2] = zr;
            else {
                const int hh = h2 - Hc;
                rhbuf[bng * Hc + hh] = zr * hbuf[bng * Hc + hh];
            }
        }
    }
}

static __device__ __forceinline__ void update_body(
    float* __restrict__ hbuf, const float* __restrict__ rhbuf,
    const float* __restrict__ GX,
    const unsigned short* __restrict__ Wu, const float* __restrict__ bu,
    const float* __restrict__ zbuf, float* __restrict__ outp,
    int tt, int bStart, int bl, int n,
    unsigned int (&Hc2)[32][64], const unsigned int (&Gt)[3][GTW],
    float (&supL)[208], float (&pS)[4][16][8])
{
    const int t = threadIdx.x;
    const int lane = t & 63;
    const int w = t >> 6;
    const int j = lane;
    const int b = bStart + bl;
    const float* hb = rhbuf + (size_t)b * Nc * Hc;
    float accA = 0.f;

    for (int c6 = 0; c6 < MCH; c6++) {
        const int mpB = c6 * 32;
        __syncthreads();
#pragma unroll
        for (int p = 0; p < 8; p++) {
            const int idx = p * 256 + t;
            const int mpl = idx >> 6;
            const int jj  = idx & 63;
            const int m0  = 2 * (mpB + mpl);
            float h0 = (m0 < Nc)     ? hb[(size_t)m0 * Hc + jj]       : 0.f;
            float h1 = (m0 + 1 < Nc) ? hb[(size_t)(m0 + 1) * Hc + jj] : 0.f;
            Hc2[mpl][jj] = packh2(h0, h1);
        }
        __syncthreads();
        if (w < 3) {
            const unsigned int* gp = &Gt[w][mpB];
#pragma unroll
            for (int mpl = 0; mpl < 32; mpl++) {
                unsigned int hu = Hc2[mpl][j];
                unsigned int gu = gp[mpl];
                accA = fdot2f(*(half2v*)&gu, *(half2v*)&hu, accA);
            }
        }
    }
    if (w < 3) supL[w * 65 + 1 + j] = accA;
    if (t < 3)
        supL[t * 65] = GX[(((size_t)tt * Bc + b) * Kc + t) * Nc + n];
    __syncthreads();

    const int c = lane & 7;
    const int g = lane >> 3;
    const unsigned short* wrow = Wu + ((size_t)bl * Nc + n) * NCu;
    float a2[8] = {0.f,0.f,0.f,0.f,0.f,0.f,0.f,0.f};

#pragma unroll
    for (int i0 = 0; i0 < SUPW; i0 += 32) {
        const int i = i0 + w * 8 + g;
        if (i < SUPW) {
            uint4 v = *(const uint4*)(wrow + (size_t)i * 64 + c * 8);
            float s = supL[i];
            a2[0] = fmaf(s, bflo(v.x), a2[0]);
            a2[1] = fmaf(s, bfhi(v.x), a2[1]);
            a2[2] = fmaf(s, bflo(v.y), a2[2]);
            a2[3] = fmaf(s, bfhi(v.y), a2[3]);
            a2[4] = fmaf(s, bflo(v.z), a2[4]);
            a2[5] = fmaf(s, bfhi(v.z), a2[5]);
            a2[6] = fmaf(s, bflo(v.w), a2[6]);
            a2[7] = fmaf(s, bfhi(v.w), a2[7]);
        }
    }
#pragma unroll
    for (int e = 0; e < 8; e++) {
        a2[e] += __shfl_xor(a2[e], 8, 64);
        a2[e] += __shfl_xor(a2[e], 16, 64);
        a2[e] += __shfl_xor(a2[e], 32, 64);
    }
    if (g == 0) {
#pragma unroll
        for (int e = 0; e < 8; e++) pS[w][c][e] = a2[e];
    }
    __syncthreads();
    if (w == 0 && g == 0) {
        const size_t bng = (size_t)b * Nc + n;
#pragma unroll
        for (int e = 0; e < 8; e++) {
            const int hh = c * 8 + e;
            const float npre = pS[0][c][e] + pS[1][c][e] + pS[2][c][e] + pS[3][c][e]
                             + bu[bng * Hc + hh];
            const float nn_t = tanhf(npre);
            const float z    = zbuf[bng * Hc + hh];
            const float hold = hbuf[bng * Hc + hh];
            const float hnew = fmaf(z, nn_t - hold, hold);
            hbuf[bng * Hc + hh] = hnew;
            outp[(((size_t)b * Tc + tt) * Nc + n) * Hc + hh] = hnew;
            if (tt == Tc - 1)
                outp[(size_t)Bc * Tc * Nc * Hc + bng * Hc + hh] = hnew;
        }
    }
}

// ---------------------------------------------------------------------------
// Standalone fused kernels (one node per block; G staged once per kernel).
__global__ __launch_bounds__(256, 6) void fused_gates_kernel(
    const float* __restrict__ G, const float* __restrict__ hbuf,
    const float* __restrict__ GX, const unsigned short* __restrict__ Wg,
    const float* __restrict__ bg, float* __restrict__ zbuf,
    float* __restrict__ rhbuf, int tt, int bStart)
{
    __shared__ unsigned int Hc2[32][64];
    __shared__ unsigned int Gt1[3][GTW];
    __shared__ float supL[208];
    __shared__ float pS[4][16][8];
    const int bx = blockIdx.x;
    const int bl = bx / Nc;
    const int n  = bx % Nc;
    stage_g_rows(G, n, Gt1);
    gates_body(hbuf, GX, Wg, bg, zbuf, rhbuf, tt, bStart, bl, n,
               Hc2, Gt1, supL, pS);
}

__global__ __launch_bounds__(256, 6) void fused_update_kernel(
    const float* __restrict__ G, const float* __restrict__ rhbuf,
    const float* __restrict__ GX, const unsigned short* __restrict__ Wu,
    const float* __restrict__ bu, const float* __restrict__ zbuf,
    float* __restrict__ hbuf, float* __restrict__ outp, int tt, int bStart)
{
    __shared__ unsigned int Hc2[32][64];
    __shared__ unsigned int Gt1[3][GTW];
    __shared__ float supL[208];
    __shared__ float pS[4][16][8];
    const int bx = blockIdx.x;
    const int bl = bx / Nc;
    const int n  = bx % Nc;
    stage_g_rows(G, n, Gt1);
    update_body(hbuf, rhbuf, GX, Wu, bu, zbuf, outp, tt, bStart, bl, n,
                Hc2, Gt1, supL, pS);
}

// ---------------------------------------------------------------------------
extern "C" void kernel_launch(void* const* d_in, const int* in_sizes, int n_in,
                              void* d_out, int out_size, void* d_ws, size_t ws_size,
                              hipStream_t stream)
{
    const float* G        = (const float*)d_in[0];
    const float* x        = (const float*)d_in[1];
    const float* meta     = (const float*)d_in[2];
    const float* lwg_w1   = (const float*)d_in[3];
    const float* lwg_b1   = (const float*)d_in[4];
    const float* lwg_w2   = (const float*)d_in[5];
    const float* lwg_b2   = (const float*)d_in[6];
    const float* lbg_w1   = (const float*)d_in[7];
    const float* lbg_b1   = (const float*)d_in[8];
    const float* lbg_w2   = (const float*)d_in[9];
    const float* lbg_b2   = (const float*)d_in[10];
    const float* lwu_w1   = (const float*)d_in[11];
    const float* lwu_b1   = (const float*)d_in[12];
    const float* lwu_w2   = (const float*)d_in[13];
    const float* lwu_b2   = (const float*)d_in[14];
    const float* lbu_w1   = (const float*)d_in[15];
    const float* lbu_b1   = (const float*)d_in[16];
    const float* lbu_w2   = (const float*)d_in[17];
    const float* lbu_b2   = (const float*)d_in[18];

    auto alignup = [](size_t b) { return (b + 255) & ~(size_t)255; };
    const size_t miscBytes =
        alignup((size_t)BNc * 2 * Hc * 4) +
        alignup((size_t)BNc * Hc * 4) +
        4 * alignup((size_t)BNc * LHc * 2) +
        alignup((size_t)NCg * 128 * 2) +
        alignup((size_t)NCu * 128 * 2) +
        alignup((size_t)128 * 128 * 2) +
        alignup((size_t)64 * 128 * 2) +
        alignup((size_t)Tc * Bc * Kc * Nc * 4) +
        3 * alignup((size_t)BNc * Hc * 4);

    int Bch = 0;
    const int cand[4] = {8, 4, 2, 1};
    for (int ci = 0; ci < 4; ci++) {
        size_t BNch = (size_t)cand[ci] * Nc;
        size_t need = miscBytes + alignup(BNch * NCg * 2) + alignup(BNch * NCu * 2);
        if (need <= ws_size) { Bch = cand[ci]; break; }
    }
    if (Bch == 0) return;
    const int nChunks = Bc / Bch;
    const int BNch    = Bch * Nc;

    char* ws = (char*)d_ws;
    size_t off = 0;
    auto alloc = [&](size_t bytes) -> char* {
        char* p = ws + off;
        off += (bytes + 255) & ~(size_t)255;
        return p;
    };
    unsigned short* Wg = (unsigned short*)alloc((size_t)BNch * NCg * 2);
    unsigned short* Wu = (unsigned short*)alloc((size_t)BNch * NCu * 2);
    float* bgbuf  = (float*)alloc((size_t)BNc * 2 * Hc * 4);
    float* bubuf  = (float*)alloc((size_t)BNc * Hc * 4);
    _Float16* r1g  = (_Float16*)alloc((size_t)BNc * LHc * 2);
    _Float16* r1bg = (_Float16*)alloc((size_t)BNc * LHc * 2);
    _Float16* r1u  = (_Float16*)alloc((size_t)BNc * LHc * 2);
    _Float16* r1bu = (_Float16*)alloc((size_t)BNc * LHc * 2);
    _Float16* w2tg  = (_Float16*)alloc((size_t)NCg * 128 * 2);
    _Float16* w2tu  = (_Float16*)alloc((size_t)NCu * 128 * 2);
    _Float16* w2tbg = (_Float16*)alloc((size_t)128 * 128 * 2);
    _Float16* w2tbu = (_Float16*)alloc((size_t)64 * 128 * 2);
    float* GX    = (float*)alloc((size_t)Tc * Bc * Kc * Nc * 4);
    float* hbuf  = (float*)alloc((size_t)BNc * Hc * 4);
    float* zbuf  = (float*)alloc((size_t)BNc * Hc * 4);
    float* rhbuf = (float*)alloc((size_t)BNc * Hc * 4);
    if (off > ws_size) return;

    float* out = (float*)d_out;

    hipMemsetAsync(hbuf, 0, (size_t)BNc * Hc * 4, stream);

    meta1_kernel<<<BNc / 4, 128, 0, stream>>>(
        meta, lwg_w1, lwg_b1, lbg_w1, lbg_b1, lwu_w1, lwu_b1, lbu_w1, lbu_b1,
        r1g, r1bg, r1u, r1bu);

    transpose_w2_kernel<<<(NCg + 63) / 64, 256, 0, stream>>>(lwg_w2, w2tg, NCg);
    transpose_w2_kernel<<<(NCu + 63) / 64, 256, 0, stream>>>(lwu_w2, w2tu, NCu);
    transpose_w2_kernel<<<2, 256, 0, stream>>>(lbg_w2, w2tbg, 2 * Hc);
    transpose_w2_kernel<<<1, 256, 0, stream>>>(lbu_w2, w2tbu, Hc);

    meta2_mfma_kernel<false><<<dim3((BNc + 63) / 64, (2 * Hc) / 64), 256, 0, stream>>>(
        r1bg, w2tbg, lbg_b2, (void*)bgbuf, 2 * Hc, BNc);
    meta2_mfma_kernel<false><<<dim3((BNc + 63) / 64, Hc / 64), 256, 0, stream>>>(
        r1bu, w2tbu, lbu_b2, (void*)bubuf, Hc, BNc);

    gx_kernel<<<dim3(Kc, 11, 3), 256, 0, stream>>>(G, x, GX);

    for (int ch = 0; ch < nChunks; ch++) {
        const int bStart  = ch * Bch;
        const int bnStart = bStart * Nc;

        meta2_mfma_kernel<true><<<dim3((BNch + 63) / 64, NCg / 64), 256, 0, stream>>>(
            r1g + (size_t)bnStart * LHc, w2tg, lwg_b2, (void*)Wg, NCg, BNch);
        meta2_mfma_kernel<true><<<dim3((BNch + 63) / 64, NCu / 64), 256, 0, stream>>>(
            r1u + (size_t)bnStart * LHc, w2tu, lwu_b2, (void*)Wu, NCu, BNch);

        for (int tt = 0; tt < Tc; tt++) {
            fused_gates_kernel<<<BNch, 256, 0, stream>>>(
                G, hbuf, GX, Wg, bgbuf, zbuf, rhbuf, tt, bStart);
            fused_update_kernel<<<BNch, 256, 0, stream>>>(
                G, rhbuf, GX, Wu, bubuf, zbuf, hbuf, out, tt, bStart);
        }
    }
}

// Round 18
// 1903.578 us; speedup vs baseline: 1.3587x; 1.1219x over previous
//
#include <hip/hip_runtime.h>
#include <hip/hip_bf16.h>
#include <hip/hip_fp8.h>
#include <stdint.h>

// Problem constants
#define Bc   16
#define Tc   12
#define Nc   325
#define Kc   3
#define Hc   64
#define MIc  127
#define LHc  128
#define BNc  (Bc*Nc)        // 5200
#define SUPW 195            // K*(D+H)
#define NCg  (SUPW*2*Hc)    // 24960
#define NCu  (SUPW*Hc)      // 12480
#define MP   163            // ceil(325/2) m-pairs
#define MCH  6              // m-pair chunks of 32
#define GTW  192            // padded Gt width (6*32)
#define WSCL 16.0f          // fp8 weight scale (power of 2)
#define WINV 0.0625f

typedef _Float16 half8  __attribute__((ext_vector_type(8)));
typedef _Float16 half2v __attribute__((ext_vector_type(2)));
typedef float    f32x4  __attribute__((ext_vector_type(4)));

static __device__ __forceinline__ float bflo(unsigned int u) {
    return __uint_as_float(u << 16);
}
static __device__ __forceinline__ float bfhi(unsigned int u) {
    return __uint_as_float(u & 0xffff0000u);
}
static __device__ __forceinline__ unsigned short f2bf(float f) {
    unsigned int u = __float_as_uint(f);
    unsigned int r = (u + 0x7fffu + ((u >> 16) & 1u)) >> 16;  // RNE
    return (unsigned short)r;
}
static __device__ __forceinline__ float fdot2f(half2v a, half2v b, float c) {
#if defined(__has_builtin)
#if __has_builtin(__builtin_amdgcn_fdot2)
    return __builtin_amdgcn_fdot2(a, b, c, false);
#else
    return c + (float)a[0] * (float)b[0] + (float)a[1] * (float)b[1];
#endif
#else
    return c + (float)a[0] * (float)b[0] + (float)a[1] * (float)b[1];
#endif
}
static __device__ __forceinline__ unsigned int packh2(float a, float b) {
    half2v h; h[0] = (_Float16)a; h[1] = (_Float16)b;
    return *(unsigned int*)&h;
}
static __device__ __forceinline__ unsigned char f2fp8(float f) {
    __hip_fp8_e4m3 t(f);
    return t.__x;
}
#if defined(__has_builtin) && __has_builtin(__builtin_amdgcn_cvt_f32_fp8)
#define FP8TOF(wrd, sel) __builtin_amdgcn_cvt_f32_fp8((wrd), (sel))
#else
static __device__ __forceinline__ float fp8tof_sw(unsigned int wrd, int sel) {
    __hip_fp8_e4m3 t; t.__x = (unsigned char)(wrd >> (sel * 8));
    return (float)t;
}
#define FP8TOF(wrd, sel) fp8tof_sw((wrd), (sel))
#endif

// ---------------------------------------------------------------------------
// Layer-1 of all four meta MLPs, 4 bn rows per block.
__global__ __launch_bounds__(128) void meta1_kernel(
    const float* __restrict__ meta,
    const float* __restrict__ w1a, const float* __restrict__ b1a,
    const float* __restrict__ w1b, const float* __restrict__ b1b,
    const float* __restrict__ w1c, const float* __restrict__ b1c,
    const float* __restrict__ w1d, const float* __restrict__ b1d,
    _Float16* __restrict__ r1a, _Float16* __restrict__ r1b,
    _Float16* __restrict__ r1c, _Float16* __restrict__ r1d)
{
    __shared__ float mrow[4][128];
    const int bn0 = blockIdx.x * 4;
    const int l   = threadIdx.x;
#pragma unroll
    for (int r = 0; r < 4; r++)
        mrow[r][l] = (l < MIc) ? meta[(size_t)(bn0 + r) * MIc + l] : 0.f;
    __syncthreads();

    const float* w1s[4] = {w1a, w1b, w1c, w1d};
    const float* b1s[4] = {b1a, b1b, b1c, b1d};
    _Float16*    os[4]  = {r1a, r1b, r1c, r1d};
#pragma unroll
    for (int s = 0; s < 4; s++) {
        const float* w = w1s[s];
        float acc[4];
        const float bv = b1s[s][l];
#pragma unroll
        for (int r = 0; r < 4; r++) acc[r] = bv;
        for (int m = 0; m < MIc; m++) {
            float wv = w[m * LHc + l];
#pragma unroll
            for (int r = 0; r < 4; r++) acc[r] = fmaf(mrow[r][m], wv, acc[r]);
        }
#pragma unroll
        for (int r = 0; r < 4; r++)
            os[s][(size_t)(bn0 + r) * LHc + l] = (_Float16)fmaxf(acc[r], 0.f);
    }
}

// ---------------------------------------------------------------------------
// w2 [128][NC] f32 -> w2t [NC][128] fp16 (transposed).
__global__ __launch_bounds__(256) void transpose_w2_kernel(
    const float* __restrict__ w2, _Float16* __restrict__ w2t, int NC)
{
    __shared__ float Ls[128][65];
    const int c0 = blockIdx.x * 64;
    const int t  = threadIdx.x;
    {
        const int c  = t & 63;
        const int kb = t >> 6;
        for (int k = kb; k < 128; k += 4) {
            int cc = c0 + c;
            Ls[k][c] = (cc < NC) ? w2[(size_t)k * NC + cc] : 0.f;
        }
    }
    __syncthreads();
    {
        const int k  = t & 127;
        const int ch = t >> 7;
        for (int c = ch; c < 64; c += 2) {
            int cc = c0 + c;
            if (cc < NC) w2t[(size_t)cc * 128 + k] = (_Float16)Ls[k][c];
        }
    }
}

// ---------------------------------------------------------------------------
// MFMA layer-2 GEMM, LDS-staged tiles. Block 256 = 4 waves, 64x64 tile.
// OM: 0 = f32 out, 1 = bf16 out, 2 = fp8-e4m3 out scaled by WSCL.
template<int OM>
__global__ __launch_bounds__(256) void meta2_mfma_kernel(
    const _Float16* __restrict__ A,
    const _Float16* __restrict__ Bt,
    const float* __restrict__ bias,
    void* __restrict__ outp, int NC, int nrows)
{
    __shared__ __align__(16) _Float16 As[64][136];
    __shared__ __align__(16) _Float16 Bs[64][136];
    __shared__ __align__(16) unsigned short Cs[64][72];   // bf16 staging
    __shared__ __align__(16) unsigned char  Cs8[64][80];  // fp8 staging
    const int t  = threadIdx.x;
    const int w  = t >> 6;
    const int l  = t & 63;
    const int r0 = blockIdx.x * 64;
    const int c0 = blockIdx.y * 64;

#pragma unroll
    for (int p = 0; p < 4; p++) {
        const int gid = p * 256 + t;
        const int row = gid >> 4;
        const int cg  = gid & 15;
        half8 av = (half8)(_Float16)0.f;
        if (r0 + row < nrows) av = *(const half8*)(A + (size_t)(r0 + row) * 128 + cg * 8);
        *(half8*)&As[row][cg * 8] = av;
        half8 bv = *(const half8*)(Bt + (size_t)(c0 + row) * 128 + cg * 8);
        *(half8*)&Bs[row][cg * 8] = bv;
    }
    __syncthreads();

    const int lr = l & 15;
    const int lk = l >> 4;

    half8 aF[4];
#pragma unroll
    for (int kk = 0; kk < 4; kk++)
        aF[kk] = *(const half8*)&As[w * 16 + lr][kk * 32 + lk * 8];

    f32x4 acc[4];
#pragma unroll
    for (int j = 0; j < 4; j++) acc[j] = (f32x4)0.f;

#pragma unroll
    for (int j = 0; j < 4; j++)
#pragma unroll
        for (int kk = 0; kk < 4; kk++) {
            half8 bF = *(const half8*)&Bs[j * 16 + lr][kk * 32 + lk * 8];
            acc[j] = __builtin_amdgcn_mfma_f32_16x16x32_f16(aF[kk], bF, acc[j], 0, 0, 0);
        }

    if (OM == 1) {
#pragma unroll
        for (int j = 0; j < 4; j++) {
            const float bv = bias[c0 + j * 16 + lr];
#pragma unroll
            for (int q = 0; q < 4; q++)
                Cs[w * 16 + lk * 4 + q][j * 16 + lr] = f2bf(acc[j][q] + bv);
        }
        __syncthreads();
        const int rl  = t >> 2;
        const int cp  = t & 3;
        const int row = r0 + rl;
        if (row < nrows) {
            const uint4* src = (const uint4*)&Cs[rl][cp * 16];
            uint4* dst = (uint4*)((unsigned short*)outp + (size_t)row * NC + c0 + cp * 16);
            dst[0] = src[0];
            dst[1] = src[1];
        }
    } else if (OM == 2) {
#pragma unroll
        for (int j = 0; j < 4; j++) {
            const float bv = bias[c0 + j * 16 + lr];
#pragma unroll
            for (int q = 0; q < 4; q++)
                Cs8[w * 16 + lk * 4 + q][j * 16 + lr] =
                    f2fp8((acc[j][q] + bv) * WSCL);
        }
        __syncthreads();
        const int rl  = t >> 2;
        const int cp  = t & 3;
        const int row = r0 + rl;
        if (row < nrows) {
            const uint4* src = (const uint4*)&Cs8[rl][cp * 16];
            uint4* dst = (uint4*)((unsigned char*)outp + (size_t)row * NC + c0 + cp * 16);
            dst[0] = src[0];
        }
    } else {
#pragma unroll
        for (int j = 0; j < 4; j++) {
            const int col = c0 + j * 16 + lr;
            const float bv = bias[col];
#pragma unroll
            for (int q = 0; q < 4; q++) {
                const int row = r0 + w * 16 + lk * 4 + q;
                if (row < nrows)
                    ((float*)outp)[(size_t)row * NC + col] = acc[j][q] + bv;
            }
        }
    }
}

// ---------------------------------------------------------------------------
// gx tiled: GX[tt,b,k,n] = sum_m G[k,n,m] * x[tb,m], tb = b*Tc+tt.
__global__ __launch_bounds__(256) void gx_kernel(
    const float* __restrict__ G, const float* __restrict__ x,
    float* __restrict__ GX)
{
    __shared__ __align__(16) float Gs[32][36];
    __shared__ __align__(16) float Xs[32][65];
    const int k   = blockIdx.x;
    const int n0  = blockIdx.y * 32;
    const int tb0 = blockIdx.z * 64;
    const int t   = threadIdx.x;
    const int j   = t & 63;
    const int ng  = t >> 6;

    float acc[8] = {0.f,0.f,0.f,0.f,0.f,0.f,0.f,0.f};

    for (int mc = 0; mc < 11; mc++) {
        const int m0 = mc * 32;
        __syncthreads();
        {
            const int ln  = t >> 3;
            const int lm0 = (t & 7) * 4;
            const int gn  = n0 + ln;
#pragma unroll
            for (int u = 0; u < 4; u++) {
                int m = m0 + lm0 + u;
                Gs[lm0 + u][ln] = (gn < Nc && m < Nc) ? G[((size_t)k * Nc + gn) * Nc + m] : 0.f;
            }
        }
        {
            const int row = t >> 2;
            const int ms  = (t & 3) * 8;
            const float* xr = x + (size_t)(tb0 + row) * Nc;
#pragma unroll
            for (int u = 0; u < 8; u++) {
                int m = m0 + ms + u;
                Xs[ms + u][row] = (m < Nc) ? xr[m] : 0.f;
            }
        }
        __syncthreads();
#pragma unroll
        for (int mm = 0; mm < 32; mm++) {
            float xv = Xs[mm][j];
            float4 ga = *(const float4*)&Gs[mm][ng * 8];
            float4 gb = *(const float4*)&Gs[mm][ng * 8 + 4];
            acc[0] = fmaf(ga.x, xv, acc[0]);
            acc[1] = fmaf(ga.y, xv, acc[1]);
            acc[2] = fmaf(ga.z, xv, acc[2]);
            acc[3] = fmaf(ga.w, xv, acc[3]);
            acc[4] = fmaf(gb.x, xv, acc[4]);
            acc[5] = fmaf(gb.y, xv, acc[5]);
            acc[6] = fmaf(gb.z, xv, acc[6]);
            acc[7] = fmaf(gb.w, xv, acc[7]);
        }
    }

    const int tb = tb0 + j;
    const int b  = tb / Tc;
    const int tv = tb % Tc;
    float* gxp = GX + (((size_t)tv * Bc + b) * Kc + k) * Nc;
#pragma unroll
    for (int i = 0; i < 8; i++) {
        int n = n0 + ng * 8 + i;
        if (n < Nc) gxp[n] = acc[i];
    }
}

// ---------------------------------------------------------------------------
static __device__ __forceinline__ void stage_g_rows(
    const float* __restrict__ G, int n, unsigned int (&Gt)[3][GTW])
{
    const int t = threadIdx.x;
    for (int idx = t; idx < 3 * GTW; idx += 256) {
        const int kk = idx / GTW;
        const int mp = idx % GTW;
        const float* gr = G + ((size_t)kk * Nc + n) * Nc;
        const int m0 = 2 * mp;
        float g0 = (m0 < Nc)     ? gr[m0]     : 0.f;
        float g1 = (m0 + 1 < Nc) ? gr[m0 + 1] : 0.f;
        Gt[kk][mp] = packh2(g0, g1);
    }
}

// ---------------------------------------------------------------------------
// Fused K1 (fp8 Wg): graph-conv(comb) + gates gemv + sigmoid.
// Phase B: lane covers 16 cols per 16B load; 7 iterations vs 13 (bf16).
__global__ __launch_bounds__(256, 6) void fused_gates_kernel(
    const float* __restrict__ G, const float* __restrict__ hbuf,
    const float* __restrict__ GX, const unsigned char* __restrict__ Wg,
    const float* __restrict__ bg, float* __restrict__ zbuf,
    float* __restrict__ rhbuf, int tt, int bStart)
{
    __shared__ unsigned int Hc2[32][64];
    __shared__ unsigned int Gt1[3][GTW];
    __shared__ float supL[208];
    __shared__ float pS[4][8][16];
    const int bx = blockIdx.x;
    const int bl = bx / Nc;
    const int n  = bx % Nc;
    const int b  = bStart + bl;
    const int t  = threadIdx.x;
    const int lane = t & 63;
    const int w  = t >> 6;
    const int j  = lane;

    stage_g_rows(G, n, Gt1);

    const float* hb = hbuf + (size_t)b * Nc * Hc;
    float accA = 0.f;

    for (int c6 = 0; c6 < MCH; c6++) {
        const int mpB = c6 * 32;
        __syncthreads();
#pragma unroll
        for (int p = 0; p < 8; p++) {
            const int idx = p * 256 + t;
            const int mpl = idx >> 6;
            const int jj  = idx & 63;
            const int m0  = 2 * (mpB + mpl);
            float h0 = (m0 < Nc)     ? hb[(size_t)m0 * Hc + jj]       : 0.f;
            float h1 = (m0 + 1 < Nc) ? hb[(size_t)(m0 + 1) * Hc + jj] : 0.f;
            Hc2[mpl][jj] = packh2(h0, h1);
        }
        __syncthreads();
        if (w < 3) {
            const unsigned int* gp = &Gt1[w][mpB];
#pragma unroll
            for (int mpl = 0; mpl < 32; mpl++) {
                unsigned int hu = Hc2[mpl][j];
                unsigned int gu = gp[mpl];
                accA = fdot2f(*(half2v*)&gu, *(half2v*)&hu, accA);
            }
        }
    }
    if (w < 3) supL[w * 65 + 1 + j] = accA;
    if (t < 3)
        supL[t * 65] = GX[(((size_t)tt * Bc + b) * Kc + t) * Nc + n];
    __syncthreads();

    // phase B: fp8 weights; c = col-group (16 cols), g = i-group
    const int c = lane & 7;
    const int g = lane >> 3;
    const unsigned char* wrow = Wg + ((size_t)bl * Nc + n) * NCg;
    float a2[16];
#pragma unroll
    for (int e = 0; e < 16; e++) a2[e] = 0.f;

#pragma unroll
    for (int i0 = 0; i0 < SUPW; i0 += 32) {
        const int i = i0 + w * 8 + g;
        if (i < SUPW) {
            uint4 v = *(const uint4*)(wrow + (size_t)i * 128 + c * 16);
            float s = supL[i];
            a2[0]  = fmaf(s, FP8TOF(v.x, 0), a2[0]);
            a2[1]  = fmaf(s, FP8TOF(v.x, 1), a2[1]);
            a2[2]  = fmaf(s, FP8TOF(v.x, 2), a2[2]);
            a2[3]  = fmaf(s, FP8TOF(v.x, 3), a2[3]);
            a2[4]  = fmaf(s, FP8TOF(v.y, 0), a2[4]);
            a2[5]  = fmaf(s, FP8TOF(v.y, 1), a2[5]);
            a2[6]  = fmaf(s, FP8TOF(v.y, 2), a2[6]);
            a2[7]  = fmaf(s, FP8TOF(v.y, 3), a2[7]);
            a2[8]  = fmaf(s, FP8TOF(v.z, 0), a2[8]);
            a2[9]  = fmaf(s, FP8TOF(v.z, 1), a2[9]);
            a2[10] = fmaf(s, FP8TOF(v.z, 2), a2[10]);
            a2[11] = fmaf(s, FP8TOF(v.z, 3), a2[11]);
            a2[12] = fmaf(s, FP8TOF(v.w, 0), a2[12]);
            a2[13] = fmaf(s, FP8TOF(v.w, 1), a2[13]);
            a2[14] = fmaf(s, FP8TOF(v.w, 2), a2[14]);
            a2[15] = fmaf(s, FP8TOF(v.w, 3), a2[15]);
        }
    }
#pragma unroll
    for (int e = 0; e < 16; e++) {
        a2[e] += __shfl_xor(a2[e], 8, 64);
        a2[e] += __shfl_xor(a2[e], 16, 64);
        a2[e] += __shfl_xor(a2[e], 32, 64);
    }
    if (g == 0) {
#pragma unroll
        for (int e = 0; e < 16; e++) pS[w][c][e] = a2[e];
    }
    __syncthreads();
    if (w == 0 && g == 0) {
        const size_t bng = (size_t)b * Nc + n;
#pragma unroll
        for (int e = 0; e < 16; e++) {
            const int h2 = c * 16 + e;
            const float pre = (pS[0][c][e] + pS[1][c][e] + pS[2][c][e] + pS[3][c][e]) * WINV
                            + bg[bng * (2 * Hc) + h2];
            const float zr  = 1.f / (1.f + expf(-pre));
            if (h2 < Hc) zbuf[bng * Hc + h2] = zr;
            else {
                const int hh = h2 - Hc;
                rhbuf[bng * Hc + hh] = zr * hbuf[bng * Hc + hh];
            }
        }
    }
}

// ---------------------------------------------------------------------------
// Fused K2 (bf16 Wu, unchanged): graph-conv(cand) + update gemv + tanh + h.
__global__ __launch_bounds__(256, 6) void fused_update_kernel(
    const float* __restrict__ G, const float* __restrict__ rhbuf,
    const float* __restrict__ GX, const unsigned short* __restrict__ Wu,
    const float* __restrict__ bu, const float* __restrict__ zbuf,
    float* __restrict__ hbuf, float* __restrict__ outp, int tt, int bStart)
{
    __shared__ unsigned int Hc2[32][64];
    __shared__ unsigned int Gt1[3][GTW];
    __shared__ float supL[208];
    __shared__ float pS[4][16][8];
    const int bx = blockIdx.x;
    const int bl = bx / Nc;
    const int n  = bx % Nc;
    const int b  = bStart + bl;
    const int t  = threadIdx.x;
    const int lane = t & 63;
    const int w  = t >> 6;
    const int j  = lane;

    stage_g_rows(G, n, Gt1);

    const float* hb = rhbuf + (size_t)b * Nc * Hc;
    float accA = 0.f;

    for (int c6 = 0; c6 < MCH; c6++) {
        const int mpB = c6 * 32;
        __syncthreads();
#pragma unroll
        for (int p = 0; p < 8; p++) {
            const int idx = p * 256 + t;
            const int mpl = idx >> 6;
            const int jj  = idx & 63;
            const int m0  = 2 * (mpB + mpl);
            float h0 = (m0 < Nc)     ? hb[(size_t)m0 * Hc + jj]       : 0.f;
            float h1 = (m0 + 1 < Nc) ? hb[(size_t)(m0 + 1) * Hc + jj] : 0.f;
            Hc2[mpl][jj] = packh2(h0, h1);
        }
        __syncthreads();
        if (w < 3) {
            const unsigned int* gp = &Gt1[w][mpB];
#pragma unroll
            for (int mpl = 0; mpl < 32; mpl++) {
                unsigned int hu = Hc2[mpl][j];
                unsigned int gu = gp[mpl];
                accA = fdot2f(*(half2v*)&gu, *(half2v*)&hu, accA);
            }
        }
    }
    if (w < 3) supL[w * 65 + 1 + j] = accA;
    if (t < 3)
        supL[t * 65] = GX[(((size_t)tt * Bc + b) * Kc + t) * Nc + n];
    __syncthreads();

    const int c = lane & 7;
    const int g = lane >> 3;
    const unsigned short* wrow = Wu + ((size_t)bl * Nc + n) * NCu;
    float a2[8] = {0.f,0.f,0.f,0.f,0.f,0.f,0.f,0.f};

#pragma unroll
    for (int i0 = 0; i0 < SUPW; i0 += 32) {
        const int i = i0 + w * 8 + g;
        if (i < SUPW) {
            uint4 v = *(const uint4*)(wrow + (size_t)i * 64 + c * 8);
            float s = supL[i];
            a2[0] = fmaf(s, bflo(v.x), a2[0]);
            a2[1] = fmaf(s, bfhi(v.x), a2[1]);
            a2[2] = fmaf(s, bflo(v.y), a2[2]);
            a2[3] = fmaf(s, bfhi(v.y), a2[3]);
            a2[4] = fmaf(s, bflo(v.z), a2[4]);
            a2[5] = fmaf(s, bfhi(v.z), a2[5]);
            a2[6] = fmaf(s, bflo(v.w), a2[6]);
            a2[7] = fmaf(s, bfhi(v.w), a2[7]);
        }
    }
#pragma unroll
    for (int e = 0; e < 8; e++) {
        a2[e] += __shfl_xor(a2[e], 8, 64);
        a2[e] += __shfl_xor(a2[e], 16, 64);
        a2[e] += __shfl_xor(a2[e], 32, 64);
    }
    if (g == 0) {
#pragma unroll
        for (int e = 0; e < 8; e++) pS[w][c][e] = a2[e];
    }
    __syncthreads();
    if (w == 0 && g == 0) {
        const size_t bng = (size_t)b * Nc + n;
#pragma unroll
        for (int e = 0; e < 8; e++) {
            const int hh = c * 8 + e;
            const float npre = pS[0][c][e] + pS[1][c][e] + pS[2][c][e] + pS[3][c][e]
                             + bu[bng * Hc + hh];
            const float nn_t = tanhf(npre);
            const float z    = zbuf[bng * Hc + hh];
            const float hold = hbuf[bng * Hc + hh];
            const float hnew = fmaf(z, nn_t - hold, hold);
            hbuf[bng * Hc + hh] = hnew;
            outp[(((size_t)b * Tc + tt) * Nc + n) * Hc + hh] = hnew;
            if (tt == Tc - 1)
                outp[(size_t)Bc * Tc * Nc * Hc + bng * Hc + hh] = hnew;
        }
    }
}

// ---------------------------------------------------------------------------
extern "C" void kernel_launch(void* const* d_in, const int* in_sizes, int n_in,
                              void* d_out, int out_size, void* d_ws, size_t ws_size,
                              hipStream_t stream)
{
    const float* G        = (const float*)d_in[0];
    const float* x        = (const float*)d_in[1];
    const float* meta     = (const float*)d_in[2];
    const float* lwg_w1   = (const float*)d_in[3];
    const float* lwg_b1   = (const float*)d_in[4];
    const float* lwg_w2   = (const float*)d_in[5];
    const float* lwg_b2   = (const float*)d_in[6];
    const float* lbg_w1   = (const float*)d_in[7];
    const float* lbg_b1   = (const float*)d_in[8];
    const float* lbg_w2   = (const float*)d_in[9];
    const float* lbg_b2   = (const float*)d_in[10];
    const float* lwu_w1   = (const float*)d_in[11];
    const float* lwu_b1   = (const float*)d_in[12];
    const float* lwu_w2   = (const float*)d_in[13];
    const float* lwu_b2   = (const float*)d_in[14];
    const float* lbu_w1   = (const float*)d_in[15];
    const float* lbu_b1   = (const float*)d_in[16];
    const float* lbu_w2   = (const float*)d_in[17];
    const float* lbu_b2   = (const float*)d_in[18];

    auto alignup = [](size_t b) { return (b + 255) & ~(size_t)255; };
    const size_t miscBytes =
        alignup((size_t)BNc * 2 * Hc * 4) +
        alignup((size_t)BNc * Hc * 4) +
        4 * alignup((size_t)BNc * LHc * 2) +
        alignup((size_t)NCg * 128 * 2) +
        alignup((size_t)NCu * 128 * 2) +
        alignup((size_t)128 * 128 * 2) +
        alignup((size_t)64 * 128 * 2) +
        alignup((size_t)Tc * Bc * Kc * Nc * 4) +
        3 * alignup((size_t)BNc * Hc * 4);

    int Bch = 0;
    const int cand[4] = {8, 4, 2, 1};
    for (int ci = 0; ci < 4; ci++) {
        size_t BNch = (size_t)cand[ci] * Nc;
        size_t need = miscBytes + alignup(BNch * NCg) + alignup(BNch * NCu * 2);
        if (need <= ws_size) { Bch = cand[ci]; break; }
    }
    if (Bch == 0) return;
    const int nChunks = Bc / Bch;
    const int BNch    = Bch * Nc;

    char* ws = (char*)d_ws;
    size_t off = 0;
    auto alloc = [&](size_t bytes) -> char* {
        char* p = ws + off;
        off += (bytes + 255) & ~(size_t)255;
        return p;
    };
    unsigned char*  Wg = (unsigned char*)alloc((size_t)BNch * NCg);       // fp8
    unsigned short* Wu = (unsigned short*)alloc((size_t)BNch * NCu * 2);  // bf16
    float* bgbuf  = (float*)alloc((size_t)BNc * 2 * Hc * 4);
    float* bubuf  = (float*)alloc((size_t)BNc * Hc * 4);
    _Float16* r1g  = (_Float16*)alloc((size_t)BNc * LHc * 2);
    _Float16* r1bg = (_Float16*)alloc((size_t)BNc * LHc * 2);
    _Float16* r1u  = (_Float16*)alloc((size_t)BNc * LHc * 2);
    _Float16* r1bu = (_Float16*)alloc((size_t)BNc * LHc * 2);
    _Float16* w2tg  = (_Float16*)alloc((size_t)NCg * 128 * 2);
    _Float16* w2tu  = (_Float16*)alloc((size_t)NCu * 128 * 2);
    _Float16* w2tbg = (_Float16*)alloc((size_t)128 * 128 * 2);
    _Float16* w2tbu = (_Float16*)alloc((size_t)64 * 128 * 2);
    float* GX    = (float*)alloc((size_t)Tc * Bc * Kc * Nc * 4);
    float* hbuf  = (float*)alloc((size_t)BNc * Hc * 4);
    float* zbuf  = (float*)alloc((size_t)BNc * Hc * 4);
    float* rhbuf = (float*)alloc((size_t)BNc * Hc * 4);
    if (off > ws_size) return;

    float* out = (float*)d_out;

    hipMemsetAsync(hbuf, 0, (size_t)BNc * Hc * 4, stream);

    meta1_kernel<<<BNc / 4, 128, 0, stream>>>(
        meta, lwg_w1, lwg_b1, lbg_w1, lbg_b1, lwu_w1, lwu_b1, lbu_w1, lbu_b1,
        r1g, r1bg, r1u, r1bu);

    transpose_w2_kernel<<<(NCg + 63) / 64, 256, 0, stream>>>(lwg_w2, w2tg, NCg);
    transpose_w2_kernel<<<(NCu + 63) / 64, 256, 0, stream>>>(lwu_w2, w2tu, NCu);
    transpose_w2_kernel<<<2, 256, 0, stream>>>(lbg_w2, w2tbg, 2 * Hc);
    transpose_w2_kernel<<<1, 256, 0, stream>>>(lbu_w2, w2tbu, Hc);

    meta2_mfma_kernel<0><<<dim3((BNc + 63) / 64, (2 * Hc) / 64), 256, 0, stream>>>(
        r1bg, w2tbg, lbg_b2, (void*)bgbuf, 2 * Hc, BNc);
    meta2_mfma_kernel<0><<<dim3((BNc + 63) / 64, Hc / 64), 256, 0, stream>>>(
        r1bu, w2tbu, lbu_b2, (void*)bubuf, Hc, BNc);

    gx_kernel<<<dim3(Kc, 11, 3), 256, 0, stream>>>(G, x, GX);

    for (int ch = 0; ch < nChunks; ch++) {
        const int bStart  = ch * Bch;
        const int bnStart = bStart * Nc;

        meta2_mfma_kernel<2><<<dim3((BNch + 63) / 64, NCg / 64), 256, 0, stream>>>(
            r1g + (size_t)bnStart * LHc, w2tg, lwg_b2, (void*)Wg, NCg, BNch);
        meta2_mfma_kernel<1><<<dim3((BNch + 63) / 64, NCu / 64), 256, 0, stream>>>(
            r1u + (size_t)bnStart * LHc, w2tu, lwu_b2, (void*)Wu, NCu, BNch);

        for (int tt = 0; tt < Tc; tt++) {
            fused_gates_kernel<<<BNch, 256, 0, stream>>>(
                G, hbuf, GX, Wg, bgbuf, zbuf, rhbuf, tt, bStart);
            fused_update_kernel<<<BNch, 256, 0, stream>>>(
                G, rhbuf, GX, Wu, bubuf, zbuf, hbuf, out, tt, bStart);
        }
    }
}

// Round 20
// 1899.471 us; speedup vs baseline: 1.3616x; 1.0022x over previous
//
#include <hip/hip_runtime.h>
#include <hip/hip_bf16.h>
#include <hip/hip_fp8.h>
#include <stdint.h>

// Problem constants
#define Bc   16
#define Tc   12
#define Nc   325
#define Kc   3
#define Hc   64
#define MIc  127
#define LHc  128
#define BNc  (Bc*Nc)        // 5200
#define SUPW 195            // K*(D+H)
#define NCg  (SUPW*2*Hc)    // 24960
#define NCu  (SUPW*Hc)      // 12480
#define MP   163            // ceil(325/2) m-pairs
#define MCH  6              // m-pair chunks of 32
#define GTW  192            // padded Gt width (6*32)
#define WSCL 16.0f          // fp8 weight scale (power of 2)
#define WINV 0.0625f

typedef _Float16 half8  __attribute__((ext_vector_type(8)));
typedef _Float16 half2v __attribute__((ext_vector_type(2)));
typedef float    f32x4  __attribute__((ext_vector_type(4)));

static __device__ __forceinline__ float bflo(unsigned int u) {
    return __uint_as_float(u << 16);
}
static __device__ __forceinline__ float bfhi(unsigned int u) {
    return __uint_as_float(u & 0xffff0000u);
}
static __device__ __forceinline__ unsigned short f2bf(float f) {
    unsigned int u = __float_as_uint(f);
    unsigned int r = (u + 0x7fffu + ((u >> 16) & 1u)) >> 16;  // RNE
    return (unsigned short)r;
}
static __device__ __forceinline__ float fdot2f(half2v a, half2v b, float c) {
#if defined(__has_builtin)
#if __has_builtin(__builtin_amdgcn_fdot2)
    return __builtin_amdgcn_fdot2(a, b, c, false);
#else
    return c + (float)a[0] * (float)b[0] + (float)a[1] * (float)b[1];
#endif
#else
    return c + (float)a[0] * (float)b[0] + (float)a[1] * (float)b[1];
#endif
}
static __device__ __forceinline__ unsigned int packh2(float a, float b) {
    half2v h; h[0] = (_Float16)a; h[1] = (_Float16)b;
    return *(unsigned int*)&h;
}
static __device__ __forceinline__ unsigned char f2fp8(float f) {
    __hip_fp8_e4m3 t(f);
    return t.__x;
}
#if defined(__has_builtin) && __has_builtin(__builtin_amdgcn_cvt_f32_fp8)
#define FP8TOF(wrd, sel) __builtin_amdgcn_cvt_f32_fp8((wrd), (sel))
#else
static __device__ __forceinline__ float fp8tof_sw(unsigned int wrd, int sel) {
    __hip_fp8_e4m3 t; t.__x = (unsigned char)(wrd >> (sel * 8));
    return (float)t;
}
#define FP8TOF(wrd, sel) fp8tof_sw((wrd), (sel))
#endif

// ---------------------------------------------------------------------------
// Layer-1 of all four meta MLPs, 4 bn rows per block.
__global__ __launch_bounds__(128) void meta1_kernel(
    const float* __restrict__ meta,
    const float* __restrict__ w1a, const float* __restrict__ b1a,
    const float* __restrict__ w1b, const float* __restrict__ b1b,
    const float* __restrict__ w1c, const float* __restrict__ b1c,
    const float* __restrict__ w1d, const float* __restrict__ b1d,
    _Float16* __restrict__ r1a, _Float16* __restrict__ r1b,
    _Float16* __restrict__ r1c, _Float16* __restrict__ r1d)
{
    __shared__ float mrow[4][128];
    const int bn0 = blockIdx.x * 4;
    const int l   = threadIdx.x;
#pragma unroll
    for (int r = 0; r < 4; r++)
        mrow[r][l] = (l < MIc) ? meta[(size_t)(bn0 + r) * MIc + l] : 0.f;
    __syncthreads();

    const float* w1s[4] = {w1a, w1b, w1c, w1d};
    const float* b1s[4] = {b1a, b1b, b1c, b1d};
    _Float16*    os[4]  = {r1a, r1b, r1c, r1d};
#pragma unroll
    for (int s = 0; s < 4; s++) {
        const float* w = w1s[s];
        float acc[4];
        const float bv = b1s[s][l];
#pragma unroll
        for (int r = 0; r < 4; r++) acc[r] = bv;
        for (int m = 0; m < MIc; m++) {
            float wv = w[m * LHc + l];
#pragma unroll
            for (int r = 0; r < 4; r++) acc[r] = fmaf(mrow[r][m], wv, acc[r]);
        }
#pragma unroll
        for (int r = 0; r < 4; r++)
            os[s][(size_t)(bn0 + r) * LHc + l] = (_Float16)fmaxf(acc[r], 0.f);
    }
}

// ---------------------------------------------------------------------------
// w2 [128][NC] f32 -> w2t [NC][128] fp16 (transposed).
__global__ __launch_bounds__(256) void transpose_w2_kernel(
    const float* __restrict__ w2, _Float16* __restrict__ w2t, int NC)
{
    __shared__ float Ls[128][65];
    const int c0 = blockIdx.x * 64;
    const int t  = threadIdx.x;
    {
        const int c  = t & 63;
        const int kb = t >> 6;
        for (int k = kb; k < 128; k += 4) {
            int cc = c0 + c;
            Ls[k][c] = (cc < NC) ? w2[(size_t)k * NC + cc] : 0.f;
        }
    }
    __syncthreads();
    {
        const int k  = t & 127;
        const int ch = t >> 7;
        for (int c = ch; c < 64; c += 2) {
            int cc = c0 + c;
            if (cc < NC) w2t[(size_t)cc * 128 + k] = (_Float16)Ls[k][c];
        }
    }
}

// ---------------------------------------------------------------------------
// MFMA layer-2 GEMM, LDS-staged tiles. Block 256 = 4 waves, 64x64 tile.
// OM: 0 = f32 out, 1 = bf16 out, 2 = fp8-e4m3 out scaled by WSCL.
template<int OM>
__global__ __launch_bounds__(256) void meta2_mfma_kernel(
    const _Float16* __restrict__ A,
    const _Float16* __restrict__ Bt,
    const float* __restrict__ bias,
    void* __restrict__ outp, int NC, int nrows)
{
    __shared__ __align__(16) _Float16 As[64][136];
    __shared__ __align__(16) _Float16 Bs[64][136];
    __shared__ __align__(16) unsigned short Cs[64][72];   // bf16 staging
    __shared__ __align__(16) unsigned char  Cs8[64][80];  // fp8 staging
    const int t  = threadIdx.x;
    const int w  = t >> 6;
    const int l  = t & 63;
    const int r0 = blockIdx.x * 64;
    const int c0 = blockIdx.y * 64;

#pragma unroll
    for (int p = 0; p < 4; p++) {
        const int gid = p * 256 + t;
        const int row = gid >> 4;
        const int cg  = gid & 15;
        half8 av = (half8)(_Float16)0.f;
        if (r0 + row < nrows) av = *(const half8*)(A + (size_t)(r0 + row) * 128 + cg * 8);
        *(half8*)&As[row][cg * 8] = av;
        half8 bv = *(const half8*)(Bt + (size_t)(c0 + row) * 128 + cg * 8);
        *(half8*)&Bs[row][cg * 8] = bv;
    }
    __syncthreads();

    const int lr = l & 15;
    const int lk = l >> 4;

    half8 aF[4];
#pragma unroll
    for (int kk = 0; kk < 4; kk++)
        aF[kk] = *(const half8*)&As[w * 16 + lr][kk * 32 + lk * 8];

    f32x4 acc[4];
#pragma unroll
    for (int j = 0; j < 4; j++) acc[j] = (f32x4)0.f;

#pragma unroll
    for (int j = 0; j < 4; j++)
#pragma unroll
        for (int kk = 0; kk < 4; kk++) {
            half8 bF = *(const half8*)&Bs[j * 16 + lr][kk * 32 + lk * 8];
            acc[j] = __builtin_amdgcn_mfma_f32_16x16x32_f16(aF[kk], bF, acc[j], 0, 0, 0);
        }

    if (OM == 1) {
#pragma unroll
        for (int j = 0; j < 4; j++) {
            const float bv = bias[c0 + j * 16 + lr];
#pragma unroll
            for (int q = 0; q < 4; q++)
                Cs[w * 16 + lk * 4 + q][j * 16 + lr] = f2bf(acc[j][q] + bv);
        }
        __syncthreads();
        const int rl  = t >> 2;
        const int cp  = t & 3;
        const int row = r0 + rl;
        if (row < nrows) {
            const uint4* src = (const uint4*)&Cs[rl][cp * 16];
            uint4* dst = (uint4*)((unsigned short*)outp + (size_t)row * NC + c0 + cp * 16);
            dst[0] = src[0];
            dst[1] = src[1];
        }
    } else if (OM == 2) {
#pragma unroll
        for (int j = 0; j < 4; j++) {
            const float bv = bias[c0 + j * 16 + lr];
#pragma unroll
            for (int q = 0; q < 4; q++)
                Cs8[w * 16 + lk * 4 + q][j * 16 + lr] =
                    f2fp8((acc[j][q] + bv) * WSCL);
        }
        __syncthreads();
        const int rl  = t >> 2;
        const int cp  = t & 3;
        const int row = r0 + rl;
        if (row < nrows) {
            const uint4* src = (const uint4*)&Cs8[rl][cp * 16];
            uint4* dst = (uint4*)((unsigned char*)outp + (size_t)row * NC + c0 + cp * 16);
            dst[0] = src[0];
        }
    } else {
#pragma unroll
        for (int j = 0; j < 4; j++) {
            const int col = c0 + j * 16 + lr;
            const float bv = bias[col];
#pragma unroll
            for (int q = 0; q < 4; q++) {
                const int row = r0 + w * 16 + lk * 4 + q;
                if (row < nrows)
                    ((float*)outp)[(size_t)row * NC + col] = acc[j][q] + bv;
            }
        }
    }
}

// ---------------------------------------------------------------------------
// gx tiled: GX[tt,b,k,n] = sum_m G[k,n,m] * x[tb,m], tb = b*Tc+tt.
__global__ __launch_bounds__(256) void gx_kernel(
    const float* __restrict__ G, const float* __restrict__ x,
    float* __restrict__ GX)
{
    __shared__ __align__(16) float Gs[32][36];
    __shared__ __align__(16) float Xs[32][65];
    const int k   = blockIdx.x;
    const int n0  = blockIdx.y * 32;
    const int tb0 = blockIdx.z * 64;
    const int t   = threadIdx.x;
    const int j   = t & 63;
    const int ng  = t >> 6;

    float acc[8] = {0.f,0.f,0.f,0.f,0.f,0.f,0.f,0.f};

    for (int mc = 0; mc < 11; mc++) {
        const int m0 = mc * 32;
        __syncthreads();
        {
            const int ln  = t >> 3;
            const int lm0 = (t & 7) * 4;
            const int gn  = n0 + ln;
#pragma unroll
            for (int u = 0; u < 4; u++) {
                int m = m0 + lm0 + u;
                Gs[lm0 + u][ln] = (gn < Nc && m < Nc) ? G[((size_t)k * Nc + gn) * Nc + m] : 0.f;
            }
        }
        {
            const int row = t >> 2;
            const int ms  = (t & 3) * 8;
            const float* xr = x + (size_t)(tb0 + row) * Nc;
#pragma unroll
            for (int u = 0; u < 8; u++) {
                int m = m0 + ms + u;
                Xs[ms + u][row] = (m < Nc) ? xr[m] : 0.f;
            }
        }
        __syncthreads();
#pragma unroll
        for (int mm = 0; mm < 32; mm++) {
            float xv = Xs[mm][j];
            float4 ga = *(const float4*)&Gs[mm][ng * 8];
            float4 gb = *(const float4*)&Gs[mm][ng * 8 + 4];
            acc[0] = fmaf(ga.x, xv, acc[0]);
            acc[1] = fmaf(ga.y, xv, acc[1]);
            acc[2] = fmaf(ga.z, xv, acc[2]);
            acc[3] = fmaf(ga.w, xv, acc[3]);
            acc[4] = fmaf(gb.x, xv, acc[4]);
            acc[5] = fmaf(gb.y, xv, acc[5]);
            acc[6] = fmaf(gb.z, xv, acc[6]);
            acc[7] = fmaf(gb.w, xv, acc[7]);
        }
    }

    const int tb = tb0 + j;
    const int b  = tb / Tc;
    const int tv = tb % Tc;
    float* gxp = GX + (((size_t)tv * Bc + b) * Kc + k) * Nc;
#pragma unroll
    for (int i = 0; i < 8; i++) {
        int n = n0 + ng * 8 + i;
        if (n < Nc) gxp[n] = acc[i];
    }
}

// ---------------------------------------------------------------------------
static __device__ __forceinline__ void stage_g_rows(
    const float* __restrict__ G, int n, unsigned int (&Gt)[3][GTW])
{
    const int t = threadIdx.x;
    for (int idx = t; idx < 3 * GTW; idx += 256) {
        const int kk = idx / GTW;
        const int mp = idx % GTW;
        const float* gr = G + ((size_t)kk * Nc + n) * Nc;
        const int m0 = 2 * mp;
        float g0 = (m0 < Nc)     ? gr[m0]     : 0.f;
        float g1 = (m0 + 1 < Nc) ? gr[m0 + 1] : 0.f;
        Gt[kk][mp] = packh2(g0, g1);
    }
}

// ---------------------------------------------------------------------------
// Fused K1 (fp8 Wg): graph-conv(comb) + gates gemv + sigmoid.
__global__ __launch_bounds__(256, 6) void fused_gates_kernel(
    const float* __restrict__ G, const float* __restrict__ hbuf,
    const float* __restrict__ GX, const unsigned char* __restrict__ Wg,
    const float* __restrict__ bg, float* __restrict__ zbuf,
    float* __restrict__ rhbuf, int tt, int bStart)
{
    __shared__ unsigned int Hc2[32][64];
    __shared__ unsigned int Gt1[3][GTW];
    __shared__ float supL[208];
    __shared__ float pS[4][8][16];
    const int bx = blockIdx.x;
    const int bl = bx / Nc;
    const int n  = bx % Nc;
    const int b  = bStart + bl;
    const int t  = threadIdx.x;
    const int lane = t & 63;
    const int w  = t >> 6;
    const int j  = lane;

    stage_g_rows(G, n, Gt1);

    const float* hb = hbuf + (size_t)b * Nc * Hc;
    float accA = 0.f;

    for (int c6 = 0; c6 < MCH; c6++) {
        const int mpB = c6 * 32;
        __syncthreads();
#pragma unroll
        for (int p = 0; p < 8; p++) {
            const int idx = p * 256 + t;
            const int mpl = idx >> 6;
            const int jj  = idx & 63;
            const int m0  = 2 * (mpB + mpl);
            float h0 = (m0 < Nc)     ? hb[(size_t)m0 * Hc + jj]       : 0.f;
            float h1 = (m0 + 1 < Nc) ? hb[(size_t)(m0 + 1) * Hc + jj] : 0.f;
            Hc2[mpl][jj] = packh2(h0, h1);
        }
        __syncthreads();
        if (w < 3) {
            const unsigned int* gp = &Gt1[w][mpB];
#pragma unroll
            for (int mpl = 0; mpl < 32; mpl++) {
                unsigned int hu = Hc2[mpl][j];
                unsigned int gu = gp[mpl];
                accA = fdot2f(*(half2v*)&gu, *(half2v*)&hu, accA);
            }
        }
    }
    if (w < 3) supL[w * 65 + 1 + j] = accA;
    if (t < 3)
        supL[t * 65] = GX[(((size_t)tt * Bc + b) * Kc + t) * Nc + n];
    __syncthreads();

    // phase B: fp8 weights; c = col-group (16 cols), g = i-group
    const int c = lane & 7;
    const int g = lane >> 3;
    const unsigned char* wrow = Wg + ((size_t)bl * Nc + n) * NCg;
    float a2[16];
#pragma unroll
    for (int e = 0; e < 16; e++) a2[e] = 0.f;

#pragma unroll
    for (int i0 = 0; i0 < SUPW; i0 += 32) {
        const int i = i0 + w * 8 + g;
        if (i < SUPW) {
            uint4 v = *(const uint4*)(wrow + (size_t)i * 128 + c * 16);
            float s = supL[i];
            a2[0]  = fmaf(s, FP8TOF(v.x, 0), a2[0]);
            a2[1]  = fmaf(s, FP8TOF(v.x, 1), a2[1]);
            a2[2]  = fmaf(s, FP8TOF(v.x, 2), a2[2]);
            a2[3]  = fmaf(s, FP8TOF(v.x, 3), a2[3]);
            a2[4]  = fmaf(s, FP8TOF(v.y, 0), a2[4]);
            a2[5]  = fmaf(s, FP8TOF(v.y, 1), a2[5]);
            a2[6]  = fmaf(s, FP8TOF(v.y, 2), a2[6]);
            a2[7]  = fmaf(s, FP8TOF(v.y, 3), a2[7]);
            a2[8]  = fmaf(s, FP8TOF(v.z, 0), a2[8]);
            a2[9]  = fmaf(s, FP8TOF(v.z, 1), a2[9]);
            a2[10] = fmaf(s, FP8TOF(v.z, 2), a2[10]);
            a2[11] = fmaf(s, FP8TOF(v.z, 3), a2[11]);
            a2[12] = fmaf(s, FP8TOF(v.w, 0), a2[12]);
            a2[13] = fmaf(s, FP8TOF(v.w, 1), a2[13]);
            a2[14] = fmaf(s, FP8TOF(v.w, 2), a2[14]);
            a2[15] = fmaf(s, FP8TOF(v.w, 3), a2[15]);
        }
    }
#pragma unroll
    for (int e = 0; e < 16; e++) {
        a2[e] += __shfl_xor(a2[e], 8, 64);
        a2[e] += __shfl_xor(a2[e], 16, 64);
        a2[e] += __shfl_xor(a2[e], 32, 64);
    }
    if (g == 0) {
#pragma unroll
        for (int e = 0; e < 16; e++) pS[w][c][e] = a2[e];
    }
    __syncthreads();
    if (w == 0 && g == 0) {
        const size_t bng = (size_t)b * Nc + n;
#pragma unroll
        for (int e = 0; e < 16; e++) {
            const int h2 = c * 16 + e;
            const float pre = (pS[0][c][e] + pS[1][c][e] + pS[2][c][e] + pS[3][c][e]) * WINV
                            + bg[bng * (2 * Hc) + h2];
            const float zr  = 1.f / (1.f + expf(-pre));
            if (h2 < Hc) zbuf[bng * Hc + h2] = zr;
            else {
                const int hh = h2 - Hc;
                rhbuf[bng * Hc + hh] = zr * hbuf[bng * Hc + hh];
            }
        }
    }
}

// ---------------------------------------------------------------------------
// Fused K2 (bf16 Wu): graph-conv(cand) + update gemv + tanh + h.
__global__ __launch_bounds__(256, 6) void fused_update_kernel(
    const float* __restrict__ G, const float* __restrict__ rhbuf,
    const float* __restrict__ GX, const unsigned short* __restrict__ Wu,
    const float* __restrict__ bu, const float* __restrict__ zbuf,
    float* __restrict__ hbuf, float* __restrict__ outp, int tt, int bStart)
{
    __shared__ unsigned int Hc2[32][64];
    __shared__ unsigned int Gt1[3][GTW];
    __shared__ float supL[208];
    __shared__ float pS[4][16][8];
    const int bx = blockIdx.x;
    const int bl = bx / Nc;
    const int n  = bx % Nc;
    const int b  = bStart + bl;
    const int t  = threadIdx.x;
    const int lane = t & 63;
    const int w  = t >> 6;
    const int j  = lane;

    stage_g_rows(G, n, Gt1);

    const float* hb = rhbuf + (size_t)b * Nc * Hc;
    float accA = 0.f;

    for (int c6 = 0; c6 < MCH; c6++) {
        const int mpB = c6 * 32;
        __syncthreads();
#pragma unroll
        for (int p = 0; p < 8; p++) {
            const int idx = p * 256 + t;
            const int mpl = idx >> 6;
            const int jj  = idx & 63;
            const int m0  = 2 * (mpB + mpl);
            float h0 = (m0 < Nc)     ? hb[(size_t)m0 * Hc + jj]       : 0.f;
            float h1 = (m0 + 1 < Nc) ? hb[(size_t)(m0 + 1) * Hc + jj] : 0.f;
            Hc2[mpl][jj] = packh2(h0, h1);
        }
        __syncthreads();
        if (w < 3) {
            const unsigned int* gp = &Gt1[w][mpB];
#pragma unroll
            for (int mpl = 0; mpl < 32; mpl++) {
                unsigned int hu = Hc2[mpl][j];
                unsigned int gu = gp[mpl];
                accA = fdot2f(*(half2v*)&gu, *(half2v*)&hu, accA);
            }
        }
    }
    if (w < 3) supL[w * 65 + 1 + j] = accA;
    if (t < 3)
        supL[t * 65] = GX[(((size_t)tt * Bc + b) * Kc + t) * Nc + n];
    __syncthreads();

    const int c = lane & 7;
    const int g = lane >> 3;
    const unsigned short* wrow = Wu + ((size_t)bl * Nc + n) * NCu;
    float a2[8] = {0.f,0.f,0.f,0.f,0.f,0.f,0.f,0.f};

#pragma unroll
    for (int i0 = 0; i0 < SUPW; i0 += 32) {
        const int i = i0 + w * 8 + g;
        if (i < SUPW) {
            uint4 v = *(const uint4*)(wrow + (size_t)i * 64 + c * 8);
            float s = supL[i];
            a2[0] = fmaf(s, bflo(v.x), a2[0]);
            a2[1] = fmaf(s, bfhi(v.x), a2[1]);
            a2[2] = fmaf(s, bflo(v.y), a2[2]);
            a2[3] = fmaf(s, bfhi(v.y), a2[3]);
            a2[4] = fmaf(s, bflo(v.z), a2[4]);
            a2[5] = fmaf(s, bfhi(v.z), a2[5]);
            a2[6] = fmaf(s, bflo(v.w), a2[6]);
            a2[7] = fmaf(s, bfhi(v.w), a2[7]);
        }
    }
#pragma unroll
    for (int e = 0; e < 8; e++) {
        a2[e] += __shfl_xor(a2[e], 8, 64);
        a2[e] += __shfl_xor(a2[e], 16, 64);
        a2[e] += __shfl_xor(a2[e], 32, 64);
    }
    if (g == 0) {
#pragma unroll
        for (int e = 0; e < 8; e++) pS[w][c][e] = a2[e];
    }
    __syncthreads();
    if (w == 0 && g == 0) {
        const size_t bng = (size_t)b * Nc + n;
#pragma unroll
        for (int e = 0; e < 8; e++) {
            const int hh = c * 8 + e;
            const float npre = pS[0][c][e] + pS[1][c][e] + pS[2][c][e] + pS[3][c][e]
                             + bu[bng * Hc + hh];
            const float nn_t = tanhf(npre);
            const float z    = zbuf[bng * Hc + hh];
            const float hold = hbuf[bng * Hc + hh];
            const float hnew = fmaf(z, nn_t - hold, hold);
            hbuf[bng * Hc + hh] = hnew;
            outp[(((size_t)b * Tc + tt) * Nc + n) * Hc + hh] = hnew;
            if (tt == Tc - 1)
                outp[(size_t)Bc * Tc * Nc * Hc + bng * Hc + hh] = hnew;
        }
    }
}

// ---------------------------------------------------------------------------
extern "C" void kernel_launch(void* const* d_in, const int* in_sizes, int n_in,
                              void* d_out, int out_size, void* d_ws, size_t ws_size,
                              hipStream_t stream)
{
    const float* G        = (const float*)d_in[0];
    const float* x        = (const float*)d_in[1];
    const float* meta     = (const float*)d_in[2];
    const float* lwg_w1   = (const float*)d_in[3];
    const float* lwg_b1   = (const float*)d_in[4];
    const float* lwg_w2   = (const float*)d_in[5];
    const float* lwg_b2   = (const float*)d_in[6];
    const float* lbg_w1   = (const float*)d_in[7];
    const float* lbg_b1   = (const float*)d_in[8];
    const float* lbg_w2   = (const float*)d_in[9];
    const float* lbg_b2   = (const float*)d_in[10];
    const float* lwu_w1   = (const float*)d_in[11];
    const float* lwu_b1   = (const float*)d_in[12];
    const float* lwu_w2   = (const float*)d_in[13];
    const float* lwu_b2   = (const float*)d_in[14];
    const float* lbu_w1   = (const float*)d_in[15];
    const float* lbu_b1   = (const float*)d_in[16];
    const float* lbu_w2   = (const float*)d_in[17];
    const float* lbu_b2   = (const float*)d_in[18];

    auto alignup = [](size_t b) { return (b + 255) & ~(size_t)255; };
    const size_t miscBytes =
        alignup((size_t)BNc * 2 * Hc * 4) +
        alignup((size_t)BNc * Hc * 4) +
        4 * alignup((size_t)BNc * LHc * 2) +
        alignup((size_t)NCg * 128 * 2) +
        alignup((size_t)NCu * 128 * 2) +
        alignup((size_t)128 * 128 * 2) +
        alignup((size_t)64 * 128 * 2) +
        alignup((size_t)Tc * Bc * Kc * Nc * 4) +
        3 * alignup((size_t)BNc * Hc * 4);

    int Bch = 0;
    const int cand[4] = {8, 4, 2, 1};
    for (int ci = 0; ci < 4; ci++) {
        size_t BNch = (size_t)cand[ci] * Nc;
        size_t need = miscBytes + alignup(BNch * NCg) + alignup(BNch * NCu * 2);
        if (need <= ws_size) { Bch = cand[ci]; break; }
    }
    if (Bch == 0) return;
    const int nChunks = Bc / Bch;
    const int BNch    = Bch * Nc;

    char* ws = (char*)d_ws;
    size_t off = 0;
    auto alloc = [&](size_t bytes) -> char* {
        char* p = ws + off;
        off += (bytes + 255) & ~(size_t)255;
        return p;
    };
    unsigned char*  Wg = (unsigned char*)alloc((size_t)BNch * NCg);       // fp8
    unsigned short* Wu = (unsigned short*)alloc((size_t)BNch * NCu * 2);  // bf16
    float* bgbuf  = (float*)alloc((size_t)BNc * 2 * Hc * 4);
    float* bubuf  = (float*)alloc((size_t)BNc * Hc * 4);
    _Float16* r1g  = (_Float16*)alloc((size_t)BNc * LHc * 2);
    _Float16* r1bg = (_Float16*)alloc((size_t)BNc * LHc * 2);
    _Float16* r1u  = (_Float16*)alloc((size_t)BNc * LHc * 2);
    _Float16* r1bu = (_Float16*)alloc((size_t)BNc * LHc * 2);
    _Float16* w2tg  = (_Float16*)alloc((size_t)NCg * 128 * 2);
    _Float16* w2tu  = (_Float16*)alloc((size_t)NCu * 128 * 2);
    _Float16* w2tbg = (_Float16*)alloc((size_t)128 * 128 * 2);
    _Float16* w2tbu = (_Float16*)alloc((size_t)64 * 128 * 2);
    float* GX    = (float*)alloc((size_t)Tc * Bc * Kc * Nc * 4);
    float* hbuf  = (float*)alloc((size_t)BNc * Hc * 4);
    float* zbuf  = (float*)alloc((size_t)BNc * Hc * 4);
    float* rhbuf = (float*)alloc((size_t)BNc * Hc * 4);
    if (off > ws_size) return;

    float* out = (float*)d_out;

    hipMemsetAsync(hbuf, 0, (size_t)BNc * Hc * 4, stream);

    meta1_kernel<<<BNc / 4, 128, 0, stream>>>(
        meta, lwg_w1, lwg_b1, lbg_w1, lbg_b1, lwu_w1, lwu_b1, lbu_w1, lbu_b1,
        r1g, r1bg, r1u, r1bu);

    transpose_w2_kernel<<<(NCg + 63) / 64, 256, 0, stream>>>(lwg_w2, w2tg, NCg);
    transpose_w2_kernel<<<(NCu + 63) / 64, 256, 0, stream>>>(lwu_w2, w2tu, NCu);
    transpose_w2_kernel<<<2, 256, 0, stream>>>(lbg_w2, w2tbg, 2 * Hc);
    transpose_w2_kernel<<<1, 256, 0, stream>>>(lbu_w2, w2tbu, Hc);

    meta2_mfma_kernel<0><<<dim3((BNc + 63) / 64, (2 * Hc) / 64), 256, 0, stream>>>(
        r1bg, w2tbg, lbg_b2, (void*)bgbuf, 2 * Hc, BNc);
    meta2_mfma_kernel<0><<<dim3((BNc + 63) / 64, Hc / 64), 256, 0, stream>>>(
        r1bu, w2tbu, lbu_b2, (void*)bubuf, Hc, BNc);

    gx_kernel<<<dim3(Kc, 11, 3), 256, 0, stream>>>(G, x, GX);

    for (int ch = 0; ch < nChunks; ch++) {
        const int bStart  = ch * Bch;
        const int bnStart = bStart * Nc;

        meta2_mfma_kernel<2><<<dim3((BNch + 63) / 64, NCg / 64), 256, 0, stream>>>(
            r1g + (size_t)bnStart * LHc, w2tg, lwg_b2, (void*)Wg, NCg, BNch);
        meta2_mfma_kernel<1><<<dim3((BNch + 63) / 64, NCu / 64), 256, 0, stream>>>(
            r1u + (size_t)bnStart * LHc, w2tu, lwu_b2, (void*)Wu, NCu, BNch);

        for (int tt = 0; tt < Tc; tt++) {
            fused_gates_kernel<<<BNch, 256, 0, stream>>>(
                G, hbuf, GX, Wg, bgbuf, zbuf, rhbuf, tt, bStart);
            fused_update_kernel<<<BNch, 256, 0, stream>>>(
                G, rhbuf, GX, Wu, bubuf, zbuf, hbuf, out, tt, bStart);
        }
    }
}